// Round 2
// baseline (533.133 us; speedup 1.0000x reference)
//
#include <hip/hip_runtime.h>
#include <hip/hip_bf16.h>

constexpr int N_  = 12288;
constexpr int E_  = 393216;
constexpr int IND = 128;
constexpr int HID = 64;
constexpr int QKD = 32;

typedef __attribute__((ext_vector_type(4))) float f4raw;

// ---------------- encoder: h = relu(relu(x@W1+b1)@W2+b2) ----------------
__global__ __launch_bounds__(256) void enc_kernel(
    const float* __restrict__ x,
    const float* __restrict__ W1, const float* __restrict__ b1,
    const float* __restrict__ W2, const float* __restrict__ b2,
    float* __restrict__ h) {
  __shared__ float W1s[IND * HID];      // 32 KB
  __shared__ float W2s[HID * HID];      // 16 KB
  __shared__ float xs[16][IND];         // 8 KB
  __shared__ float hs[16][HID + 1];     // ~4 KB
  int tid = threadIdx.x;
  for (int i = tid; i < IND * HID; i += 256) W1s[i] = W1[i];
  for (int i = tid; i < HID * HID; i += 256) W2s[i] = W2[i];
  int row0 = blockIdx.x * 16;
  const float4* xg = (const float4*)(x + (size_t)row0 * IND);
  float4* xsv = (float4*)&xs[0][0];
  for (int i = tid; i < 16 * IND / 4; i += 256) xsv[i] = xg[i];
  __syncthreads();
  int lane = tid & 63, sub = tid >> 6;
  float b1l = b1[lane], b2l = b2[lane];
  for (int rr = sub; rr < 16; rr += 4) {
    float acc = b1l;
#pragma unroll
    for (int i = 0; i < IND; ++i) acc = fmaf(xs[rr][i], W1s[i * HID + lane], acc);
    hs[rr][lane] = fmaxf(acc, 0.f);
  }
  __syncthreads();
  for (int rr = sub; rr < 16; rr += 4) {
    float acc = b2l;
#pragma unroll
    for (int i = 0; i < HID; ++i) acc = fmaf(hs[rr][i], W2s[i * HID + lane], acc);
    h[(size_t)(row0 + rr) * HID + lane] = fmaxf(acc, 0.f);
  }
}

// ---------------- degree + col histogram ----------------
__global__ void hist_kernel(const int* __restrict__ row, const int* __restrict__ col,
                            int* degRow, int* cntCol) {
  int e = blockIdx.x * 256 + threadIdx.x;
  if (e < E_) {
    atomicAdd(&degRow[row[e]], 1);
    atomicAdd(&cntCol[col[e]], 1);
  }
}

__global__ void dinv_kernel(const int* __restrict__ deg, float* __restrict__ d) {
  int i = blockIdx.x * 256 + threadIdx.x;
  if (i < N_) {
    float dg = (float)max(deg[i], 1);
    d[i] = 1.0f / sqrtf(dg);
  }
}

// ---------------- exclusive scan over cntCol (single block) ----------------
__global__ __launch_bounds__(1024) void scan_kernel(const int* __restrict__ cnt,
                                                    int* __restrict__ off,
                                                    int* __restrict__ cursor) {
  __shared__ int sd[1024];
  int tid = threadIdx.x;
  int base = tid * 12;
  int local[12];
  int s = 0;
#pragma unroll
  for (int i = 0; i < 12; ++i) { local[i] = cnt[base + i]; s += local[i]; }
  sd[tid] = s;
  __syncthreads();
  for (int o = 1; o < 1024; o <<= 1) {
    int v = (tid >= o) ? sd[tid - o] : 0;
    __syncthreads();
    sd[tid] += v;
    __syncthreads();
  }
  int run = sd[tid] - s;  // exclusive prefix
#pragma unroll
  for (int i = 0; i < 12; ++i) {
    off[base + i] = run;
    cursor[base + i] = run;
    run += local[i];
  }
  if (tid == 1023) off[N_] = run;
}

// ---------------- CSR scatter (sorted by col) ----------------
__global__ void scatter_kernel(const int* __restrict__ row, const int* __restrict__ col,
                               int* cursor, int* __restrict__ csrRow) {
  int e = blockIdx.x * 256 + threadIdx.x;
  if (e < E_) {
    int c = col[e];
    int p = atomicAdd(&cursor[c], 1);
    csrRow[p] = row[e];
  }
}

// ---------------- xd = x * dinv (row-wise) ----------------
__global__ void scale_kernel(const float* __restrict__ x, const float* __restrict__ d,
                             float* __restrict__ xd) {
  int i = blockIdx.x * 256 + threadIdx.x;
  xd[i] = x[i] * d[i >> 6];
}

// ---------------- y = x - (segsum(xd[row], col)) * dinv ----------------
__global__ __launch_bounds__(256) void lap_kernel(
    const float* __restrict__ x, const float* __restrict__ xd,
    const float* __restrict__ d, const int* __restrict__ off,
    const int* __restrict__ csrRow, float* __restrict__ y) {
  int lane = threadIdx.x & 63, sub = threadIdx.x >> 6;
  int c = blockIdx.x * 4 + sub;
  int s0 = off[c], s1 = off[c + 1];
  float acc = 0.f;
  for (int i = s0; i < s1; ++i) {
    int r = csrRow[i];
    acc += xd[(size_t)r * HID + lane];
  }
  y[(size_t)c * HID + lane] = x[(size_t)c * HID + lane] - acc * d[c];
}

// ---------------- masked sum of h_ori rows + weight count ----------------
__global__ __launch_bounds__(256) void qred_kernel(const float* __restrict__ h,
                                                   const unsigned char* __restrict__ mask,
                                                   float* gsum) {
  __shared__ float part[4][HID];
  __shared__ float wpart[4];
  int lane = threadIdx.x & 63, sub = threadIdx.x >> 6;
  int base = blockIdx.x * 256 + sub * 64;
  float acc = 0.f, wl = 0.f;
  for (int j = 0; j < 64; ++j) {
    int n = base + j;
    float w = mask[n] ? 0.f : 1.f;
    acc = fmaf(w, h[(size_t)n * HID + lane], acc);
    wl += w;
  }
  part[sub][lane] = acc;
  if (lane == 0) wpart[sub] = wl;
  __syncthreads();
  if (sub == 0) {
    float t = part[0][lane] + part[1][lane] + part[2][lane] + part[3][lane];
    atomicAdd(&gsum[lane], t);
    if (lane == 0) atomicAdd(&gsum[64], wpart[0] + wpart[1] + wpart[2] + wpart[3]);
  }
}

// ---------------- q_global -> kq = scale*(Wk@qg), sb = scale*(bk.qg) ----------------
__global__ void qfinal_kernel(const float* __restrict__ gsum,
                              const float* __restrict__ Wq, const float* __restrict__ bq,
                              const float* __restrict__ Wk, const float* __restrict__ bk,
                              float* __restrict__ kq) {
  __shared__ float qg[QKD];
  int tid = threadIdx.x;  // 64 threads
  float wsum = gsum[64];
  float inv = 1.0f / fmaxf(wsum, 1.0f);
  if (tid < QKD) {
    float a = bq[tid] * wsum;
    for (int d0 = 0; d0 < HID; ++d0) a = fmaf(gsum[d0], Wq[d0 * QKD + tid], a);
    qg[tid] = a * inv;
  }
  __syncthreads();
  const float scale = 0.125f;  // 1/sqrt(HID)
  float a = 0.f;
  for (int q = 0; q < QKD; ++q) a = fmaf(Wk[tid * QKD + q], qg[q], a);
  kq[tid] = a * scale;
  if (tid == 0) {
    float sb = 0.f;
    for (int q = 0; q < QKD; ++q) sb = fmaf(bk[q], qg[q], sb);
    kq[64] = sb * scale;
  }
}

// ---------------- attention over 3 hop-features + z = zpre@Wv + bv ----------------
__global__ __launch_bounds__(256) void attnz_kernel(
    const float* __restrict__ h, const float* __restrict__ l1,
    const float* __restrict__ l2, const float* __restrict__ kqv,
    const float* __restrict__ Wv, const float* __restrict__ bv,
    float* __restrict__ z) {
  __shared__ float Wvs[HID * HID];  // 16 KB
  __shared__ float zs[4][HID];
  int tid = threadIdx.x;
  for (int i = tid; i < HID * HID; i += 256) Wvs[i] = Wv[i];
  int lane = tid & 63, sub = tid >> 6;
  int n = blockIdx.x * 4 + sub;
  size_t idx = (size_t)n * HID + lane;
  float hv = h[idx], v1 = l1[idx], v2 = l2[idx];
  float av = 2.f * hv - v1;
  float kql = kqv[lane];
  float sb = kqv[64];
  float s0 = av * kql, s1 = v1 * kql, s2 = v2 * kql;
  for (int o = 32; o; o >>= 1) {
    s0 += __shfl_xor(s0, o);
    s1 += __shfl_xor(s1, o);
    s2 += __shfl_xor(s2, o);
  }
  s0 += sb; s1 += sb; s2 += sb;
  float m = fmaxf(s0, fmaxf(s1, s2));
  float e0 = __expf(s0 - m), e1 = __expf(s1 - m), e2 = __expf(s2 - m);
  float isum = 1.f / (e0 + e1 + e2);
  float zp = (e0 * av + e1 * v1 + e2 * v2) * isum;
  zs[sub][lane] = zp;
  __syncthreads();
  float acc = bv[lane];
#pragma unroll
  for (int i = 0; i < HID; ++i) acc = fmaf(zs[sub][i], Wvs[i * HID + lane], acc);
  z[idx] = acc;
}

// ---------------- x_hat = z @ Wdx + bdx ----------------
__global__ __launch_bounds__(256) void xhat_kernel(const float* __restrict__ z,
                                                   const float* __restrict__ Wdx,
                                                   const float* __restrict__ bdx,
                                                   float* __restrict__ out) {
  __shared__ float Ws[HID * IND];  // 32 KB
  __shared__ float zsh[8][HID];
  int tid = threadIdx.x;
  for (int i = tid; i < HID * IND; i += 256) Ws[i] = Wdx[i];
  int n0 = blockIdx.x * 8;
  for (int i = tid; i < 8 * HID; i += 256) ((float*)zsh)[i] = z[(size_t)n0 * HID + i];
  __syncthreads();
  int j = tid & 127, sub = tid >> 7;
  float bj = bdx[j];
  for (int it = 0; it < 4; ++it) {
    int r = it * 2 + sub;
    float acc = bj;
#pragma unroll
    for (int i = 0; i < HID; ++i) acc = fmaf(zsh[r][i], Ws[i * IND + j], acc);
    out[(size_t)(n0 + r) * IND + j] = acc;
  }
}

// ---------------- adj_hat = z @ z^T, 128x128 tiles, 8x8 per thread ----------------
__global__ __launch_bounds__(256) void adj_kernel(const float* __restrict__ z,
                                                  float* __restrict__ out) {
  __shared__ float As[HID][128];  // 32 KB
  __shared__ float Bs[HID][128];  // 32 KB
  int tid = threadIdx.x;
  int rb = blockIdx.y, cb = blockIdx.x;
  {
    const float4* za = (const float4*)(z + (size_t)rb * 128 * HID);
    const float4* zb = (const float4*)(z + (size_t)cb * 128 * HID);
    for (int c = tid; c < 2048; c += 256) {
      int kc = c & 15, m = c >> 4;
      float4 va = za[m * 16 + kc];
      float4 vb = zb[m * 16 + kc];
      int k = kc * 4;
#pragma unroll
      for (int j = 0; j < 4; ++j) {
        int colidx = m ^ (((k + j) & 7) << 3);
        As[k + j][colidx] = ((const float*)&va)[j];
        Bs[k + j][colidx] = ((const float*)&vb)[j];
      }
    }
  }
  __syncthreads();
  int tx = tid & 15, ty = tid >> 4;
  float acc[8][8];
#pragma unroll
  for (int i = 0; i < 8; ++i)
#pragma unroll
    for (int j = 0; j < 8; ++j) acc[i][j] = 0.f;

#pragma unroll 8
  for (int k = 0; k < HID; ++k) {
    int sw = (k & 7) << 3;
    const float4* ap = (const float4*)&As[k][(ty * 8) ^ sw];
    const float4* bp = (const float4*)&Bs[k][(tx * 8) ^ sw];
    float4 a0 = ap[0], a1 = ap[1];
    float4 b0 = bp[0], b1 = bp[1];
    float a[8] = {a0.x, a0.y, a0.z, a0.w, a1.x, a1.y, a1.z, a1.w};
    float b[8] = {b0.x, b0.y, b0.z, b0.w, b1.x, b1.y, b1.z, b1.w};
#pragma unroll
    for (int i = 0; i < 8; ++i)
#pragma unroll
      for (int j = 0; j < 8; ++j) acc[i][j] = fmaf(a[i], b[j], acc[i][j]);
  }

#pragma unroll
  for (int i = 0; i < 8; ++i) {
    size_t r = (size_t)(rb * 128 + ty * 8 + i);
    float* orow = out + r * N_ + cb * 128 + tx * 8;
    f4raw v0 = {acc[i][0], acc[i][1], acc[i][2], acc[i][3]};
    f4raw v1 = {acc[i][4], acc[i][5], acc[i][6], acc[i][7]};
    __builtin_nontemporal_store(v0, (f4raw*)orow);
    __builtin_nontemporal_store(v1, ((f4raw*)orow) + 1);
  }
}

extern "C" void kernel_launch(void* const* d_in, const int* in_sizes, int n_in,
                              void* d_out, int out_size, void* d_ws, size_t ws_size,
                              hipStream_t stream) {
  const float* x_train = (const float*)d_in[0];
  const float* x_ori   = (const float*)d_in[1];
  const int*   ei      = (const int*)d_in[2];
  const unsigned char* mask = (const unsigned char*)d_in[3];
  const float* W1  = (const float*)d_in[4];
  const float* b1  = (const float*)d_in[5];
  const float* W2  = (const float*)d_in[6];
  const float* b2  = (const float*)d_in[7];
  const float* Wq  = (const float*)d_in[8];
  const float* bq  = (const float*)d_in[9];
  const float* Wk  = (const float*)d_in[10];
  const float* bk  = (const float*)d_in[11];
  const float* Wv  = (const float*)d_in[12];
  const float* bv  = (const float*)d_in[13];
  const float* Wdx = (const float*)d_in[14];
  const float* bdx = (const float*)d_in[15];

  char* ws = (char*)d_ws;
  size_t o = 0;
  auto alloc = [&](size_t bytes) -> void* {
    void* p = ws + o;
    o += (bytes + 255) & ~(size_t)255;
    return p;
  };
  float* h_ori  = (float*)alloc((size_t)N_ * HID * 4);
  float* h_tr   = (float*)alloc((size_t)N_ * HID * 4);
  float* lap1   = (float*)alloc((size_t)N_ * HID * 4);
  float* lap2   = (float*)alloc((size_t)N_ * HID * 4);
  float* xd     = (float*)alloc((size_t)N_ * HID * 4);
  float* z      = (float*)alloc((size_t)N_ * HID * 4);
  float* dinv   = (float*)alloc((size_t)N_ * 4);
  int*   degRow = (int*)alloc((size_t)N_ * 4);
  int*   cntCol = (int*)alloc((size_t)N_ * 4);
  int*   off    = (int*)alloc((size_t)(N_ + 1) * 4);
  int*   cursor = (int*)alloc((size_t)N_ * 4);
  int*   csrRow = (int*)alloc((size_t)E_ * 4);
  float* gsum   = (float*)alloc(65 * 4);
  float* kq     = (float*)alloc(65 * 4);

  const int* row = ei;
  const int* col = ei + E_;

  (void)hipMemsetAsync(degRow, 0, (size_t)N_ * 4, stream);
  (void)hipMemsetAsync(cntCol, 0, (size_t)N_ * 4, stream);
  (void)hipMemsetAsync(gsum, 0, 65 * 4, stream);

  enc_kernel<<<N_ / 16, 256, 0, stream>>>(x_ori, W1, b1, W2, b2, h_ori);
  enc_kernel<<<N_ / 16, 256, 0, stream>>>(x_train, W1, b1, W2, b2, h_tr);
  hist_kernel<<<E_ / 256, 256, 0, stream>>>(row, col, degRow, cntCol);
  dinv_kernel<<<N_ / 256, 256, 0, stream>>>(degRow, dinv);
  scan_kernel<<<1, 1024, 0, stream>>>(cntCol, off, cursor);
  scatter_kernel<<<E_ / 256, 256, 0, stream>>>(row, col, cursor, csrRow);

  scale_kernel<<<(N_ * HID) / 256, 256, 0, stream>>>(h_tr, dinv, xd);
  lap_kernel<<<N_ / 4, 256, 0, stream>>>(h_tr, xd, dinv, off, csrRow, lap1);
  scale_kernel<<<(N_ * HID) / 256, 256, 0, stream>>>(lap1, dinv, xd);
  lap_kernel<<<N_ / 4, 256, 0, stream>>>(lap1, xd, dinv, off, csrRow, lap2);

  qred_kernel<<<N_ / 256, 256, 0, stream>>>(h_ori, mask, gsum);
  qfinal_kernel<<<1, 64, 0, stream>>>(gsum, Wq, bq, Wk, bk, kq);
  attnz_kernel<<<N_ / 4, 256, 0, stream>>>(h_tr, lap1, lap2, kq, Wv, bv, z);

  float* outp = (float*)d_out;
  xhat_kernel<<<N_ / 8, 256, 0, stream>>>(z, Wdx, bdx, outp);
  adj_kernel<<<dim3(96, 96), 256, 0, stream>>>(z, outp + (size_t)N_ * IND);
}

// Round 3
// 323.746 us; speedup vs baseline: 1.6468x; 1.6468x over previous
//
#include <hip/hip_runtime.h>
#include <hip/hip_bf16.h>

constexpr int N_  = 12288;
constexpr int E_  = 393216;
constexpr int IND = 128;
constexpr int HID = 64;
constexpr int QKD = 32;

typedef __attribute__((ext_vector_type(8))) __bf16 bf16x8;
typedef __attribute__((ext_vector_type(16))) float f32x16;

// ---------------- encoder: h = relu(relu(x@W1+b1)@W2+b2) ----------------
__global__ __launch_bounds__(256) void enc_kernel(
    const float* __restrict__ x,
    const float* __restrict__ W1, const float* __restrict__ b1,
    const float* __restrict__ W2, const float* __restrict__ b2,
    float* __restrict__ h) {
  __shared__ float W1s[IND * HID];      // 32 KB
  __shared__ float W2s[HID * HID];      // 16 KB
  __shared__ float xs[16][IND];         // 8 KB
  __shared__ float hs[16][HID + 1];     // ~4 KB
  int tid = threadIdx.x;
  for (int i = tid; i < IND * HID; i += 256) W1s[i] = W1[i];
  for (int i = tid; i < HID * HID; i += 256) W2s[i] = W2[i];
  int row0 = blockIdx.x * 16;
  const float4* xg = (const float4*)(x + (size_t)row0 * IND);
  float4* xsv = (float4*)&xs[0][0];
  for (int i = tid; i < 16 * IND / 4; i += 256) xsv[i] = xg[i];
  __syncthreads();
  int lane = tid & 63, sub = tid >> 6;
  float b1l = b1[lane], b2l = b2[lane];
  for (int rr = sub; rr < 16; rr += 4) {
    float acc = b1l;
#pragma unroll
    for (int i = 0; i < IND; ++i) acc = fmaf(xs[rr][i], W1s[i * HID + lane], acc);
    hs[rr][lane] = fmaxf(acc, 0.f);
  }
  __syncthreads();
  for (int rr = sub; rr < 16; rr += 4) {
    float acc = b2l;
#pragma unroll
    for (int i = 0; i < HID; ++i) acc = fmaf(hs[rr][i], W2s[i * HID + lane], acc);
    h[(size_t)(row0 + rr) * HID + lane] = fmaxf(acc, 0.f);
  }
}

// ---------------- degree + col histogram ----------------
__global__ void hist_kernel(const int* __restrict__ row, const int* __restrict__ col,
                            int* degRow, int* cntCol) {
  int e = blockIdx.x * 256 + threadIdx.x;
  if (e < E_) {
    atomicAdd(&degRow[row[e]], 1);
    atomicAdd(&cntCol[col[e]], 1);
  }
}

__global__ void dinv_kernel(const int* __restrict__ deg, float* __restrict__ d) {
  int i = blockIdx.x * 256 + threadIdx.x;
  if (i < N_) {
    float dg = (float)max(deg[i], 1);
    d[i] = 1.0f / sqrtf(dg);
  }
}

// ---------------- exclusive scan over cntCol (single block) ----------------
__global__ __launch_bounds__(1024) void scan_kernel(const int* __restrict__ cnt,
                                                    int* __restrict__ off,
                                                    int* __restrict__ cursor) {
  __shared__ int sd[1024];
  int tid = threadIdx.x;
  int base = tid * 12;
  int local[12];
  int s = 0;
#pragma unroll
  for (int i = 0; i < 12; ++i) { local[i] = cnt[base + i]; s += local[i]; }
  sd[tid] = s;
  __syncthreads();
  for (int o = 1; o < 1024; o <<= 1) {
    int v = (tid >= o) ? sd[tid - o] : 0;
    __syncthreads();
    sd[tid] += v;
    __syncthreads();
  }
  int run = sd[tid] - s;  // exclusive prefix
#pragma unroll
  for (int i = 0; i < 12; ++i) {
    off[base + i] = run;
    cursor[base + i] = run;
    run += local[i];
  }
  if (tid == 1023) off[N_] = run;
}

// ---------------- CSR scatter (sorted by col) ----------------
__global__ void scatter_kernel(const int* __restrict__ row, const int* __restrict__ col,
                               int* cursor, int* __restrict__ csrRow) {
  int e = blockIdx.x * 256 + threadIdx.x;
  if (e < E_) {
    int c = col[e];
    int p = atomicAdd(&cursor[c], 1);
    csrRow[p] = row[e];
  }
}

// ---------------- xd = x * dinv (row-wise) ----------------
__global__ void scale_kernel(const float* __restrict__ x, const float* __restrict__ d,
                             float* __restrict__ xd) {
  int i = blockIdx.x * 256 + threadIdx.x;
  xd[i] = x[i] * d[i >> 6];
}

// ---------------- y = x - (segsum(xd[row], col)) * dinv ----------------
__global__ __launch_bounds__(256) void lap_kernel(
    const float* __restrict__ x, const float* __restrict__ xd,
    const float* __restrict__ d, const int* __restrict__ off,
    const int* __restrict__ csrRow, float* __restrict__ y) {
  int lane = threadIdx.x & 63, sub = threadIdx.x >> 6;
  int c = blockIdx.x * 4 + sub;
  int s0 = off[c], s1 = off[c + 1];
  float acc = 0.f;
  for (int i = s0; i < s1; ++i) {
    int r = csrRow[i];
    acc += xd[(size_t)r * HID + lane];
  }
  y[(size_t)c * HID + lane] = x[(size_t)c * HID + lane] - acc * d[c];
}

// ---------------- masked sum of h_ori rows + weight count ----------------
__global__ __launch_bounds__(256) void qred_kernel(const float* __restrict__ h,
                                                   const unsigned char* __restrict__ mask,
                                                   float* gsum) {
  __shared__ float part[4][HID];
  __shared__ float wpart[4];
  int lane = threadIdx.x & 63, sub = threadIdx.x >> 6;
  int base = blockIdx.x * 256 + sub * 64;
  float acc = 0.f, wl = 0.f;
  for (int j = 0; j < 64; ++j) {
    int n = base + j;
    float w = mask[n] ? 0.f : 1.f;
    acc = fmaf(w, h[(size_t)n * HID + lane], acc);
    wl += w;
  }
  part[sub][lane] = acc;
  if (lane == 0) wpart[sub] = wl;
  __syncthreads();
  if (sub == 0) {
    float t = part[0][lane] + part[1][lane] + part[2][lane] + part[3][lane];
    atomicAdd(&gsum[lane], t);
    if (lane == 0) atomicAdd(&gsum[64], wpart[0] + wpart[1] + wpart[2] + wpart[3]);
  }
}

// ---------------- q_global -> kq = scale*(Wk@qg), sb = scale*(bk.qg) ----------------
__global__ void qfinal_kernel(const float* __restrict__ gsum,
                              const float* __restrict__ Wq, const float* __restrict__ bq,
                              const float* __restrict__ Wk, const float* __restrict__ bk,
                              float* __restrict__ kq) {
  __shared__ float qg[QKD];
  int tid = threadIdx.x;  // 64 threads
  float wsum = gsum[64];
  float inv = 1.0f / fmaxf(wsum, 1.0f);
  if (tid < QKD) {
    float a = bq[tid] * wsum;
    for (int d0 = 0; d0 < HID; ++d0) a = fmaf(gsum[d0], Wq[d0 * QKD + tid], a);
    qg[tid] = a * inv;
  }
  __syncthreads();
  const float scale = 0.125f;  // 1/sqrt(HID)
  float a = 0.f;
  for (int q = 0; q < QKD; ++q) a = fmaf(Wk[tid * QKD + q], qg[q], a);
  kq[tid] = a * scale;
  if (tid == 0) {
    float sb = 0.f;
    for (int q = 0; q < QKD; ++q) sb = fmaf(bk[q], qg[q], sb);
    kq[64] = sb * scale;
  }
}

// ---------------- attention over 3 hop-features + z = zpre@Wv + bv ----------------
// also emits bf16 copy of z for the MFMA adj kernel
__global__ __launch_bounds__(256) void attnz_kernel(
    const float* __restrict__ h, const float* __restrict__ l1,
    const float* __restrict__ l2, const float* __restrict__ kqv,
    const float* __restrict__ Wv, const float* __restrict__ bv,
    float* __restrict__ z, __hip_bfloat16* __restrict__ zb) {
  __shared__ float Wvs[HID * HID];  // 16 KB
  __shared__ float zs[4][HID];
  int tid = threadIdx.x;
  for (int i = tid; i < HID * HID; i += 256) Wvs[i] = Wv[i];
  int lane = tid & 63, sub = tid >> 6;
  int n = blockIdx.x * 4 + sub;
  size_t idx = (size_t)n * HID + lane;
  float hv = h[idx], v1 = l1[idx], v2 = l2[idx];
  float av = 2.f * hv - v1;
  float kql = kqv[lane];
  float sb = kqv[64];
  float s0 = av * kql, s1 = v1 * kql, s2 = v2 * kql;
  for (int o = 32; o; o >>= 1) {
    s0 += __shfl_xor(s0, o);
    s1 += __shfl_xor(s1, o);
    s2 += __shfl_xor(s2, o);
  }
  s0 += sb; s1 += sb; s2 += sb;
  float m = fmaxf(s0, fmaxf(s1, s2));
  float e0 = __expf(s0 - m), e1 = __expf(s1 - m), e2 = __expf(s2 - m);
  float isum = 1.f / (e0 + e1 + e2);
  float zp = (e0 * av + e1 * v1 + e2 * v2) * isum;
  zs[sub][lane] = zp;
  __syncthreads();
  float acc = bv[lane];
#pragma unroll
  for (int i = 0; i < HID; ++i) acc = fmaf(zs[sub][i], Wvs[i * HID + lane], acc);
  z[idx] = acc;
  zb[idx] = __float2bfloat16(acc);
}

// ---------------- x_hat = z @ Wdx + bdx ----------------
__global__ __launch_bounds__(256) void xhat_kernel(const float* __restrict__ z,
                                                   const float* __restrict__ Wdx,
                                                   const float* __restrict__ bdx,
                                                   float* __restrict__ out) {
  __shared__ float Ws[HID * IND];  // 32 KB
  __shared__ float zsh[8][HID];
  int tid = threadIdx.x;
  for (int i = tid; i < HID * IND; i += 256) Ws[i] = Wdx[i];
  int n0 = blockIdx.x * 8;
  for (int i = tid; i < 8 * HID; i += 256) ((float*)zsh)[i] = z[(size_t)n0 * HID + i];
  __syncthreads();
  int j = tid & 127, sub = tid >> 7;
  float bj = bdx[j];
  for (int it = 0; it < 4; ++it) {
    int r = it * 2 + sub;
    float acc = bj;
#pragma unroll
    for (int i = 0; i < HID; ++i) acc = fmaf(zsh[r][i], Ws[i * IND + j], acc);
    out[(size_t)(n0 + r) * IND + j] = acc;
  }
}

// ---------------- adj_hat = z @ z^T via bf16 MFMA ----------------
// block = 256 thr = 4 waves; block tile 128x128; wave tile 64x64 (2x2 mfma 32x32)
// A and B fragments use IDENTICAL per-lane load patterns (row/col = lane&31,
// k = kk*16 + 8*(lane>>5) + j), which makes the z@z^T result invariant to any
// k-permutation ambiguity in the operand layout. C/D layout is the HW-verified
// col=lane&31, row=(reg&3)+8*(reg>>2)+4*(lane>>5).
__global__ __launch_bounds__(256) void adj_mfma_kernel(
    const __hip_bfloat16* __restrict__ zb, float* __restrict__ out) {
  const __bf16* z = (const __bf16*)zb;
  int tid = threadIdx.x;
  int wave = tid >> 6, lane = tid & 63;
  int wr = wave >> 1, wc = wave & 1;
  int rb = blockIdx.y, cb = blockIdx.x;
  int lr = lane & 31, hi = lane >> 5;

  size_t arow0 = (size_t)(rb * 128 + wr * 64 + lr) * HID;
  size_t arow1 = arow0 + (size_t)32 * HID;
  size_t brow0 = (size_t)(cb * 128 + wc * 64 + lr) * HID;
  size_t brow1 = brow0 + (size_t)32 * HID;
  int kbase = hi * 8;

  f32x16 acc00 = (f32x16)(0.f), acc01 = (f32x16)(0.f);
  f32x16 acc10 = (f32x16)(0.f), acc11 = (f32x16)(0.f);

#pragma unroll
  for (int kk = 0; kk < 4; ++kk) {
    int k0 = kk * 16 + kbase;
    bf16x8 a0 = *(const bf16x8*)(z + arow0 + k0);
    bf16x8 a1 = *(const bf16x8*)(z + arow1 + k0);
    bf16x8 b0 = *(const bf16x8*)(z + brow0 + k0);
    bf16x8 b1 = *(const bf16x8*)(z + brow1 + k0);
    acc00 = __builtin_amdgcn_mfma_f32_32x32x16_bf16(a0, b0, acc00, 0, 0, 0);
    acc01 = __builtin_amdgcn_mfma_f32_32x32x16_bf16(a0, b1, acc01, 0, 0, 0);
    acc10 = __builtin_amdgcn_mfma_f32_32x32x16_bf16(a1, b0, acc10, 0, 0, 0);
    acc11 = __builtin_amdgcn_mfma_f32_32x32x16_bf16(a1, b1, acc11, 0, 0, 0);
  }

  int colb = cb * 128 + wc * 64 + lr;
  int rowb = rb * 128 + wr * 64 + 4 * hi;
#pragma unroll
  for (int reg = 0; reg < 16; ++reg) {
    int rr = (reg & 3) + 8 * (reg >> 2);
    size_t r0 = (size_t)(rowb + rr);
    __builtin_nontemporal_store(acc00[reg], out + r0 * N_ + colb);
    __builtin_nontemporal_store(acc01[reg], out + r0 * N_ + colb + 32);
    __builtin_nontemporal_store(acc10[reg], out + (r0 + 32) * N_ + colb);
    __builtin_nontemporal_store(acc11[reg], out + (r0 + 32) * N_ + colb + 32);
  }
}

extern "C" void kernel_launch(void* const* d_in, const int* in_sizes, int n_in,
                              void* d_out, int out_size, void* d_ws, size_t ws_size,
                              hipStream_t stream) {
  const float* x_train = (const float*)d_in[0];
  const float* x_ori   = (const float*)d_in[1];
  const int*   ei      = (const int*)d_in[2];
  const unsigned char* mask = (const unsigned char*)d_in[3];
  const float* W1  = (const float*)d_in[4];
  const float* b1  = (const float*)d_in[5];
  const float* W2  = (const float*)d_in[6];
  const float* b2  = (const float*)d_in[7];
  const float* Wq  = (const float*)d_in[8];
  const float* bq  = (const float*)d_in[9];
  const float* Wk  = (const float*)d_in[10];
  const float* bk  = (const float*)d_in[11];
  const float* Wv  = (const float*)d_in[12];
  const float* bv  = (const float*)d_in[13];
  const float* Wdx = (const float*)d_in[14];
  const float* bdx = (const float*)d_in[15];

  char* ws = (char*)d_ws;
  size_t o = 0;
  auto alloc = [&](size_t bytes) -> void* {
    void* p = ws + o;
    o += (bytes + 255) & ~(size_t)255;
    return p;
  };
  float* h_ori  = (float*)alloc((size_t)N_ * HID * 4);
  float* h_tr   = (float*)alloc((size_t)N_ * HID * 4);
  float* lap1   = (float*)alloc((size_t)N_ * HID * 4);
  float* lap2   = (float*)alloc((size_t)N_ * HID * 4);
  float* xd     = (float*)alloc((size_t)N_ * HID * 4);
  float* z      = (float*)alloc((size_t)N_ * HID * 4);
  __hip_bfloat16* zb = (__hip_bfloat16*)alloc((size_t)N_ * HID * 2);
  float* dinv   = (float*)alloc((size_t)N_ * 4);
  int*   degRow = (int*)alloc((size_t)N_ * 4);
  int*   cntCol = (int*)alloc((size_t)N_ * 4);
  int*   off    = (int*)alloc((size_t)(N_ + 1) * 4);
  int*   cursor = (int*)alloc((size_t)N_ * 4);
  int*   csrRow = (int*)alloc((size_t)E_ * 4);
  float* gsum   = (float*)alloc(65 * 4);
  float* kq     = (float*)alloc(65 * 4);

  const int* row = ei;
  const int* col = ei + E_;

  (void)hipMemsetAsync(degRow, 0, (size_t)N_ * 4, stream);
  (void)hipMemsetAsync(cntCol, 0, (size_t)N_ * 4, stream);
  (void)hipMemsetAsync(gsum, 0, 65 * 4, stream);

  enc_kernel<<<N_ / 16, 256, 0, stream>>>(x_ori, W1, b1, W2, b2, h_ori);
  enc_kernel<<<N_ / 16, 256, 0, stream>>>(x_train, W1, b1, W2, b2, h_tr);
  hist_kernel<<<E_ / 256, 256, 0, stream>>>(row, col, degRow, cntCol);
  dinv_kernel<<<N_ / 256, 256, 0, stream>>>(degRow, dinv);
  scan_kernel<<<1, 1024, 0, stream>>>(cntCol, off, cursor);
  scatter_kernel<<<E_ / 256, 256, 0, stream>>>(row, col, cursor, csrRow);

  scale_kernel<<<(N_ * HID) / 256, 256, 0, stream>>>(h_tr, dinv, xd);
  lap_kernel<<<N_ / 4, 256, 0, stream>>>(h_tr, xd, dinv, off, csrRow, lap1);
  scale_kernel<<<(N_ * HID) / 256, 256, 0, stream>>>(lap1, dinv, xd);
  lap_kernel<<<N_ / 4, 256, 0, stream>>>(lap1, xd, dinv, off, csrRow, lap2);

  qred_kernel<<<N_ / 256, 256, 0, stream>>>(h_ori, mask, gsum);
  qfinal_kernel<<<1, 64, 0, stream>>>(gsum, Wq, bq, Wk, bk, kq);
  attnz_kernel<<<N_ / 4, 256, 0, stream>>>(h_tr, lap1, lap2, kq, Wv, bv, z, zb);

  float* outp = (float*)d_out;
  xhat_kernel<<<N_ / 8, 256, 0, stream>>>(z, Wdx, bdx, outp);
  adj_mfma_kernel<<<dim3(96, 96), 256, 0, stream>>>(zb, outp + (size_t)N_ * IND);
}

// Round 4
// 316.077 us; speedup vs baseline: 1.6867x; 1.0243x over previous
//
#include <hip/hip_runtime.h>
#include <hip/hip_bf16.h>

constexpr int N_  = 12288;
constexpr int E_  = 393216;
constexpr int IND = 128;
constexpr int HID = 64;
constexpr int QKD = 32;

typedef __attribute__((ext_vector_type(8))) __bf16 bf16x8;
typedef __attribute__((ext_vector_type(16))) float f32x16;

// ---------------- fused encoder (both inputs) + masked q-reduction + xd ----------------
// grid = 2 * N/16 blocks of 256. bid < N/16 : x_ori -> h_ori (+ gsum acc)
//                                 else      : x_train -> h_tr, xd = h_tr*dinv
__global__ __launch_bounds__(256) void enc2_kernel(
    const float* __restrict__ xo, const float* __restrict__ xt,
    const float* __restrict__ W1, const float* __restrict__ b1,
    const float* __restrict__ W2, const float* __restrict__ b2,
    const float* __restrict__ dinv, const unsigned char* __restrict__ mask,
    float* __restrict__ h_ori, float* __restrict__ h_tr,
    float* __restrict__ xd, float* __restrict__ gsum) {
  __shared__ float W1s[IND * HID];   // 32 KB
  __shared__ float W2s[HID * HID];   // 16 KB
  __shared__ float xs[16][IND];      // 8 KB
  __shared__ float hs[16][HID];      // 4 KB
  __shared__ float part[4][HID];     // 1 KB
  int tid = threadIdx.x;
  bool ori = (int)blockIdx.x < (N_ / 16);
  int row0 = (ori ? blockIdx.x : blockIdx.x - N_ / 16) * 16;
  const float* x = ori ? xo : xt;
  for (int i = tid; i < IND * HID; i += 256) W1s[i] = W1[i];
  for (int i = tid; i < HID * HID; i += 256) W2s[i] = W2[i];
  {
    const float4* xg = (const float4*)(x + (size_t)row0 * IND);
    float4* xsv = (float4*)&xs[0][0];
    for (int i = tid; i < 16 * IND / 4; i += 256) xsv[i] = xg[i];
  }
  __syncthreads();
  int lane = tid & 63, sub = tid >> 6;
  float b1l = b1[lane], b2l = b2[lane];
  float a0 = b1l, a1 = b1l, a2 = b1l, a3 = b1l;
#pragma unroll 8
  for (int i = 0; i < IND; ++i) {
    float w = W1s[i * HID + lane];
    a0 = fmaf(xs[sub][i], w, a0);
    a1 = fmaf(xs[sub + 4][i], w, a1);
    a2 = fmaf(xs[sub + 8][i], w, a2);
    a3 = fmaf(xs[sub + 12][i], w, a3);
  }
  hs[sub][lane]      = fmaxf(a0, 0.f);
  hs[sub + 4][lane]  = fmaxf(a1, 0.f);
  hs[sub + 8][lane]  = fmaxf(a2, 0.f);
  hs[sub + 12][lane] = fmaxf(a3, 0.f);
  // rows of sub are read only by the same wave -> no block barrier needed
  float c0 = b2l, c1 = b2l, c2 = b2l, c3 = b2l;
#pragma unroll 8
  for (int i = 0; i < HID; ++i) {
    float w = W2s[i * HID + lane];
    c0 = fmaf(hs[sub][i], w, c0);
    c1 = fmaf(hs[sub + 4][i], w, c1);
    c2 = fmaf(hs[sub + 8][i], w, c2);
    c3 = fmaf(hs[sub + 12][i], w, c3);
  }
  c0 = fmaxf(c0, 0.f); c1 = fmaxf(c1, 0.f);
  c2 = fmaxf(c2, 0.f); c3 = fmaxf(c3, 0.f);
  size_t base = (size_t)row0 * HID + lane;
  if (ori) {
    h_ori[base + (size_t)(sub)      * HID] = c0;
    h_ori[base + (size_t)(sub + 4)  * HID] = c1;
    h_ori[base + (size_t)(sub + 8)  * HID] = c2;
    h_ori[base + (size_t)(sub + 12) * HID] = c3;
    float w0 = mask[row0 + sub] ? 0.f : 1.f;
    float w1 = mask[row0 + sub + 4] ? 0.f : 1.f;
    float w2 = mask[row0 + sub + 8] ? 0.f : 1.f;
    float w3 = mask[row0 + sub + 12] ? 0.f : 1.f;
    part[sub][lane] = w0 * c0 + w1 * c1 + w2 * c2 + w3 * c3;
    __syncthreads();
    if (sub == 0) {
      float t = part[0][lane] + part[1][lane] + part[2][lane] + part[3][lane];
      atomicAdd(&gsum[lane], t);
    }
    if (tid == 0) {
      float wl = 0.f;
      for (int r = 0; r < 16; ++r) wl += mask[row0 + r] ? 0.f : 1.f;
      atomicAdd(&gsum[64], wl);
    }
  } else {
    float d0 = dinv[row0 + sub], d1 = dinv[row0 + sub + 4];
    float d2 = dinv[row0 + sub + 8], d3 = dinv[row0 + sub + 12];
    h_tr[base + (size_t)(sub)      * HID] = c0;
    h_tr[base + (size_t)(sub + 4)  * HID] = c1;
    h_tr[base + (size_t)(sub + 8)  * HID] = c2;
    h_tr[base + (size_t)(sub + 12) * HID] = c3;
    xd[base + (size_t)(sub)      * HID] = c0 * d0;
    xd[base + (size_t)(sub + 4)  * HID] = c1 * d1;
    xd[base + (size_t)(sub + 8)  * HID] = c2 * d2;
    xd[base + (size_t)(sub + 12) * HID] = c3 * d3;
  }
}

// ---------------- degree + col histogram ----------------
__global__ void hist_kernel(const int* __restrict__ row, const int* __restrict__ col,
                            int* degRow, int* cntCol) {
  int e = blockIdx.x * 256 + threadIdx.x;
  if (e < E_) {
    atomicAdd(&degRow[row[e]], 1);
    atomicAdd(&cntCol[col[e]], 1);
  }
}

// ---------------- exclusive scan over cntCol + dinv (single block) ----------------
__global__ __launch_bounds__(1024) void scan_kernel(const int* __restrict__ cnt,
                                                    const int* __restrict__ deg,
                                                    int* __restrict__ off,
                                                    int* __restrict__ cursor,
                                                    float* __restrict__ dinv) {
  __shared__ int sd[1024];
  int tid = threadIdx.x;
  int base = tid * 12;
  int local[12];
  int s = 0;
#pragma unroll
  for (int i = 0; i < 12; ++i) { local[i] = cnt[base + i]; s += local[i]; }
  sd[tid] = s;
  __syncthreads();
  for (int o = 1; o < 1024; o <<= 1) {
    int v = (tid >= o) ? sd[tid - o] : 0;
    __syncthreads();
    sd[tid] += v;
    __syncthreads();
  }
  int run = sd[tid] - s;  // exclusive prefix
#pragma unroll
  for (int i = 0; i < 12; ++i) {
    off[base + i] = run;
    cursor[base + i] = run;
    run += local[i];
  }
  if (tid == 1023) off[N_] = run;
#pragma unroll
  for (int i = 0; i < 12; ++i) {
    int ii = base + i;
    dinv[ii] = rsqrtf((float)max(deg[ii], 1));
  }
}

// ---------------- CSR scatter (sorted by col) ----------------
__global__ void scatter_kernel(const int* __restrict__ row, const int* __restrict__ col,
                               int* cursor, int* __restrict__ csrRow) {
  int e = blockIdx.x * 256 + threadIdx.x;
  if (e < E_) {
    int c = col[e];
    int p = atomicAdd(&cursor[c], 1);
    csrRow[p] = row[e];
  }
}

// ---------------- y = x - segsum(xd[row], col)*dinv ; optionally yd = y*dinv ----------------
template <bool EMIT_D>
__global__ __launch_bounds__(256) void lap_kernel(
    const float* __restrict__ x, const float* __restrict__ xd,
    const float* __restrict__ d, const int* __restrict__ off,
    const int* __restrict__ csrRow, float* __restrict__ y, float* __restrict__ yd) {
  int lane = threadIdx.x & 63, sub = threadIdx.x >> 6;
  int c = blockIdx.x * 4 + sub;
  int s0 = off[c], s1 = off[c + 1];
  float acc = 0.f;
  for (int i = s0; i < s1; ++i) {
    int r = csrRow[i];
    acc += xd[(size_t)r * HID + lane];
  }
  float dc = d[c];
  float v = x[(size_t)c * HID + lane] - acc * dc;
  y[(size_t)c * HID + lane] = v;
  if (EMIT_D) yd[(size_t)c * HID + lane] = v * dc;
}

// ---------------- q_global -> kq = scale*(Wk@qg), sb = scale*(bk.qg) ----------------
__global__ void qfinal_kernel(const float* __restrict__ gsum,
                              const float* __restrict__ Wq, const float* __restrict__ bq,
                              const float* __restrict__ Wk, const float* __restrict__ bk,
                              float* __restrict__ kq) {
  __shared__ float qg[QKD];
  int tid = threadIdx.x;  // 64 threads
  float wsum = gsum[64];
  float inv = 1.0f / fmaxf(wsum, 1.0f);
  if (tid < QKD) {
    float a = bq[tid] * wsum;
    for (int d0 = 0; d0 < HID; ++d0) a = fmaf(gsum[d0], Wq[d0 * QKD + tid], a);
    qg[tid] = a * inv;
  }
  __syncthreads();
  const float scale = 0.125f;  // 1/sqrt(HID)
  float a = 0.f;
  for (int q = 0; q < QKD; ++q) a = fmaf(Wk[tid * QKD + q], qg[q], a);
  kq[tid] = a * scale;
  if (tid == 0) {
    float sb = 0.f;
    for (int q = 0; q < QKD; ++q) sb = fmaf(bk[q], qg[q], sb);
    kq[64] = sb * scale;
  }
}

// ---------------- attention + z = zpre@Wv+bv + x_hat = z@Wdx+bdx + zb ----------------
// 8 rows per block of 256 (4 waves); z never hits HBM in fp32.
__global__ __launch_bounds__(256) void attnz_xhat_kernel(
    const float* __restrict__ h, const float* __restrict__ l1,
    const float* __restrict__ l2, const float* __restrict__ kqv,
    const float* __restrict__ Wv, const float* __restrict__ bv,
    const float* __restrict__ Wdx, const float* __restrict__ bdx,
    float* __restrict__ xhat, __hip_bfloat16* __restrict__ zb) {
  __shared__ float Wvs[HID * HID];   // 16 KB
  __shared__ float Wds[HID * IND];   // 32 KB
  __shared__ float zp[8][HID];       // 2 KB
  __shared__ float zs[8][HID];       // 2 KB
  int tid = threadIdx.x;
  for (int i = tid; i < HID * HID; i += 256) Wvs[i] = Wv[i];
  for (int i = tid; i < HID * IND; i += 256) Wds[i] = Wdx[i];
  int lane = tid & 63, sub = tid >> 6;
  int n0 = blockIdx.x * 8;
  float kql = kqv[lane], sbias = kqv[64];
#pragma unroll
  for (int k = 0; k < 2; ++k) {
    int r = sub * 2 + k;
    size_t idx = (size_t)(n0 + r) * HID + lane;
    float hv = h[idx], v1 = l1[idx], v2 = l2[idx];
    float av = 2.f * hv - v1;
    float s0 = av * kql, s1 = v1 * kql, s2 = v2 * kql;
    for (int o = 32; o; o >>= 1) {
      s0 += __shfl_xor(s0, o);
      s1 += __shfl_xor(s1, o);
      s2 += __shfl_xor(s2, o);
    }
    s0 += sbias; s1 += sbias; s2 += sbias;
    float m = fmaxf(s0, fmaxf(s1, s2));
    float e0 = __expf(s0 - m), e1 = __expf(s1 - m), e2 = __expf(s2 - m);
    float is = 1.f / (e0 + e1 + e2);
    zp[r][lane] = (e0 * av + e1 * v1 + e2 * v2) * is;
  }
  __syncthreads();  // Wvs/Wds ready; zp rows are same-wave
#pragma unroll
  for (int k = 0; k < 2; ++k) {
    int r = sub * 2 + k;
    float acc = bv[lane];
#pragma unroll 8
    for (int i = 0; i < HID; ++i) acc = fmaf(zp[r][i], Wvs[i * HID + lane], acc);
    zs[r][lane] = acc;
    zb[(size_t)(n0 + r) * HID + lane] = __float2bfloat16(acc);
  }
  __syncthreads();  // zs read across waves below
  int j = tid & 127, half = tid >> 7;
  float bj = bdx[j];
#pragma unroll
  for (int k = 0; k < 4; ++k) {
    int r = k * 2 + half;
    float acc = bj;
#pragma unroll 8
    for (int i = 0; i < HID; ++i) acc = fmaf(zs[r][i], Wds[i * IND + j], acc);
    xhat[(size_t)(n0 + r) * IND + j] = acc;
  }
}

// ---------------- adj_hat = z @ z^T via bf16 MFMA ----------------
__global__ __launch_bounds__(256) void adj_mfma_kernel(
    const __hip_bfloat16* __restrict__ zbp, float* __restrict__ out) {
  const __bf16* z = (const __bf16*)zbp;
  int tid = threadIdx.x;
  int wave = tid >> 6, lane = tid & 63;
  int wr = wave >> 1, wc = wave & 1;
  int rb = blockIdx.y, cb = blockIdx.x;
  int lr = lane & 31, hi = lane >> 5;

  size_t arow0 = (size_t)(rb * 128 + wr * 64 + lr) * HID;
  size_t arow1 = arow0 + (size_t)32 * HID;
  size_t brow0 = (size_t)(cb * 128 + wc * 64 + lr) * HID;
  size_t brow1 = brow0 + (size_t)32 * HID;
  int kbase = hi * 8;

  f32x16 acc00 = (f32x16)(0.f), acc01 = (f32x16)(0.f);
  f32x16 acc10 = (f32x16)(0.f), acc11 = (f32x16)(0.f);

#pragma unroll
  for (int kk = 0; kk < 4; ++kk) {
    int k0 = kk * 16 + kbase;
    bf16x8 a0 = *(const bf16x8*)(z + arow0 + k0);
    bf16x8 a1 = *(const bf16x8*)(z + arow1 + k0);
    bf16x8 b0 = *(const bf16x8*)(z + brow0 + k0);
    bf16x8 b1 = *(const bf16x8*)(z + brow1 + k0);
    acc00 = __builtin_amdgcn_mfma_f32_32x32x16_bf16(a0, b0, acc00, 0, 0, 0);
    acc01 = __builtin_amdgcn_mfma_f32_32x32x16_bf16(a0, b1, acc01, 0, 0, 0);
    acc10 = __builtin_amdgcn_mfma_f32_32x32x16_bf16(a1, b0, acc10, 0, 0, 0);
    acc11 = __builtin_amdgcn_mfma_f32_32x32x16_bf16(a1, b1, acc11, 0, 0, 0);
  }

  int colb = cb * 128 + wc * 64 + lr;
  int rowb = rb * 128 + wr * 64 + 4 * hi;
#pragma unroll
  for (int reg = 0; reg < 16; ++reg) {
    int rr = (reg & 3) + 8 * (reg >> 2);
    size_t r0 = (size_t)(rowb + rr);
    __builtin_nontemporal_store(acc00[reg], out + r0 * N_ + colb);
    __builtin_nontemporal_store(acc01[reg], out + r0 * N_ + colb + 32);
    __builtin_nontemporal_store(acc10[reg], out + (r0 + 32) * N_ + colb);
    __builtin_nontemporal_store(acc11[reg], out + (r0 + 32) * N_ + colb + 32);
  }
}

extern "C" void kernel_launch(void* const* d_in, const int* in_sizes, int n_in,
                              void* d_out, int out_size, void* d_ws, size_t ws_size,
                              hipStream_t stream) {
  const float* x_train = (const float*)d_in[0];
  const float* x_ori   = (const float*)d_in[1];
  const int*   ei      = (const int*)d_in[2];
  const unsigned char* mask = (const unsigned char*)d_in[3];
  const float* W1  = (const float*)d_in[4];
  const float* b1  = (const float*)d_in[5];
  const float* W2  = (const float*)d_in[6];
  const float* b2  = (const float*)d_in[7];
  const float* Wq  = (const float*)d_in[8];
  const float* bq  = (const float*)d_in[9];
  const float* Wk  = (const float*)d_in[10];
  const float* bk  = (const float*)d_in[11];
  const float* Wv  = (const float*)d_in[12];
  const float* bv  = (const float*)d_in[13];
  const float* Wdx = (const float*)d_in[14];
  const float* bdx = (const float*)d_in[15];

  char* ws = (char*)d_ws;
  size_t o = 0;
  auto alloc = [&](size_t bytes) -> void* {
    void* p = ws + o;
    o += (bytes + 255) & ~(size_t)255;
    return p;
  };
  float* h_ori  = (float*)alloc((size_t)N_ * HID * 4);
  float* h_tr   = (float*)alloc((size_t)N_ * HID * 4);
  float* lap1   = (float*)alloc((size_t)N_ * HID * 4);
  float* lap1d  = (float*)alloc((size_t)N_ * HID * 4);
  float* lap2   = (float*)alloc((size_t)N_ * HID * 4);
  float* xd     = (float*)alloc((size_t)N_ * HID * 4);
  __hip_bfloat16* zb = (__hip_bfloat16*)alloc((size_t)N_ * HID * 2);
  float* dinv   = (float*)alloc((size_t)N_ * 4);
  // contiguous zero region: degRow | cntCol | gsum(65)
  int*   zero0  = (int*)alloc((size_t)(2 * N_ + 65) * 4);
  int*   degRow = zero0;
  int*   cntCol = zero0 + N_;
  float* gsum   = (float*)(zero0 + 2 * N_);
  int*   off    = (int*)alloc((size_t)(N_ + 1) * 4);
  int*   cursor = (int*)alloc((size_t)N_ * 4);
  int*   csrRow = (int*)alloc((size_t)E_ * 4);
  float* kq     = (float*)alloc(65 * 4);

  const int* row = ei;
  const int* col = ei + E_;

  (void)hipMemsetAsync(zero0, 0, (size_t)(2 * N_ + 65) * 4, stream);

  hist_kernel<<<E_ / 256, 256, 0, stream>>>(row, col, degRow, cntCol);
  scan_kernel<<<1, 1024, 0, stream>>>(cntCol, degRow, off, cursor, dinv);
  scatter_kernel<<<E_ / 256, 256, 0, stream>>>(row, col, cursor, csrRow);

  enc2_kernel<<<2 * (N_ / 16), 256, 0, stream>>>(x_ori, x_train, W1, b1, W2, b2,
                                                 dinv, mask, h_ori, h_tr, xd, gsum);

  lap_kernel<true><<<N_ / 4, 256, 0, stream>>>(h_tr, xd, dinv, off, csrRow, lap1, lap1d);
  lap_kernel<false><<<N_ / 4, 256, 0, stream>>>(lap1, lap1d, dinv, off, csrRow, lap2, nullptr);

  qfinal_kernel<<<1, 64, 0, stream>>>(gsum, Wq, bq, Wk, bk, kq);

  float* outp = (float*)d_out;
  attnz_xhat_kernel<<<N_ / 8, 256, 0, stream>>>(h_tr, lap1, lap2, kq, Wv, bv,
                                                Wdx, bdx, outp, zb);
  adj_mfma_kernel<<<dim3(96, 96), 256, 0, stream>>>(zb, outp + (size_t)N_ * IND);
}

// Round 5
// 299.075 us; speedup vs baseline: 1.7826x; 1.0568x over previous
//
#include <hip/hip_runtime.h>
#include <hip/hip_bf16.h>

constexpr int N_  = 12288;
constexpr int E_  = 393216;
constexpr int IND = 128;
constexpr int HID = 64;
constexpr int QKD = 32;

typedef __attribute__((ext_vector_type(4))) float f4raw;
typedef __attribute__((ext_vector_type(8))) __bf16 bf16x8;
typedef __attribute__((ext_vector_type(4))) __bf16 bf16x4;
typedef __attribute__((ext_vector_type(16))) float f32x16;

// LDS bf16 tile helpers: [32 rows][64 cols] = 128 B/row, XOR-swizzled
// (byte ^= (row&7)<<4) so stride-128B column reads spread across banks.
__device__ inline bf16x8 lds_read_bf8(const char* base, int row, int k) {
  int off = (row * 128 + k * 2) ^ ((row & 7) << 4);
  uint4 u = *(const uint4*)(base + off);
  union { uint4 u; bf16x8 v; } c; c.u = u; return c.v;
}
__device__ inline void lds_write_bf(char* base, int row, int col, __bf16 v) {
  int off = (row * 128 + col * 2) ^ ((row & 7) << 4);
  *(__bf16*)(base + off) = v;
}

// ---------------- prep: bf16 copies (x) + bf16 transposed weights ----------------
__global__ __launch_bounds__(256) void prep_kernel(
    const float* __restrict__ xo, const float* __restrict__ xt,
    const float* __restrict__ W1, const float* __restrict__ W2,
    const float* __restrict__ Wv, const float* __restrict__ Wdx,
    __bf16* __restrict__ xb, __bf16* __restrict__ W1T, __bf16* __restrict__ W2T,
    __bf16* __restrict__ WvT, __bf16* __restrict__ WdxT) {
  int b = blockIdx.x, tid = threadIdx.x;
  if (b < 1536) {
    // xb[0..N) = ori, xb[N..2N) = train; 2048 elems per block, no straddle
    size_t base = (size_t)b * 2048 + (size_t)tid * 8;
    const size_t half = (size_t)N_ * IND;
    const float* src = (base < half) ? (xo + base) : (xt + (base - half));
    f4raw v0 = *(const f4raw*)(src);
    f4raw v1 = *(const f4raw*)(src + 4);
    bf16x8 o;
    o[0] = (__bf16)v0.x; o[1] = (__bf16)v0.y; o[2] = (__bf16)v0.z; o[3] = (__bf16)v0.w;
    o[4] = (__bf16)v1.x; o[5] = (__bf16)v1.y; o[6] = (__bf16)v1.z; o[7] = (__bf16)v1.w;
    *(bf16x8*)(xb + base) = o;
  } else if (b == 1536) {
    for (int e = tid; e < IND * HID; e += 256) {
      int c = e >> 7, k = e & 127;           // W1T[c][k] (c<64,k<128)
      W1T[e] = (__bf16)W1[k * HID + c];
    }
  } else if (b == 1537) {
    for (int e = tid; e < HID * HID; e += 256) {
      int c = e >> 6, k = e & 63;
      W2T[e] = (__bf16)W2[k * HID + c];
    }
  } else if (b == 1538) {
    for (int e = tid; e < HID * HID; e += 256) {
      int c = e >> 6, k = e & 63;
      WvT[e] = (__bf16)Wv[k * HID + c];
    }
  } else {
    for (int e = tid; e < HID * IND; e += 256) {
      int c = e >> 6, k = e & 63;            // WdxT[c][k] (c<128,k<64)
      WdxT[e] = (__bf16)Wdx[k * IND + c];
    }
  }
}

// ---------------- degree + col histogram ----------------
__global__ void hist_kernel(const int* __restrict__ row, const int* __restrict__ col,
                            int* degRow, int* cntCol) {
  int e = blockIdx.x * 256 + threadIdx.x;
  if (e < E_) {
    atomicAdd(&degRow[row[e]], 1);
    atomicAdd(&cntCol[col[e]], 1);
  }
}

// ---------------- exclusive scan over cntCol + dinv (single block) ----------------
__global__ __launch_bounds__(1024) void scan_kernel(const int* __restrict__ cnt,
                                                    const int* __restrict__ deg,
                                                    int* __restrict__ off,
                                                    int* __restrict__ cursor,
                                                    float* __restrict__ dinv) {
  __shared__ int sd[1024];
  int tid = threadIdx.x;
  int base = tid * 12;
  int local[12];
  int s = 0;
#pragma unroll
  for (int i = 0; i < 12; ++i) { local[i] = cnt[base + i]; s += local[i]; }
  sd[tid] = s;
  __syncthreads();
  for (int o = 1; o < 1024; o <<= 1) {
    int v = (tid >= o) ? sd[tid - o] : 0;
    __syncthreads();
    sd[tid] += v;
    __syncthreads();
  }
  int run = sd[tid] - s;
#pragma unroll
  for (int i = 0; i < 12; ++i) {
    off[base + i] = run;
    cursor[base + i] = run;
    run += local[i];
  }
  if (tid == 1023) off[N_] = run;
#pragma unroll
  for (int i = 0; i < 12; ++i) {
    int ii = base + i;
    dinv[ii] = rsqrtf((float)max(deg[ii], 1));
  }
}

// ---------------- CSR scatter (sorted by col) ----------------
__global__ void scatter_kernel(const int* __restrict__ row, const int* __restrict__ col,
                               int* cursor, int* __restrict__ csrRow) {
  int e = blockIdx.x * 256 + threadIdx.x;
  if (e < E_) {
    int c = col[e];
    int p = atomicAdd(&cursor[c], 1);
    csrRow[p] = row[e];
  }
}

// ---------------- fused MFMA encoder + masked q-reduction + xd ----------------
// 32 rows/block, 128 threads (2 waves = col halves). blocks [0,384) ori, [384,768) train.
__global__ __launch_bounds__(128) void enc_mfma_kernel(
    const __bf16* __restrict__ xb,
    const __bf16* __restrict__ W1T, const float* __restrict__ b1,
    const __bf16* __restrict__ W2T, const float* __restrict__ b2,
    const float* __restrict__ dinv, const unsigned char* __restrict__ mask,
    float* __restrict__ h_tr, float* __restrict__ xd, float* __restrict__ gsum) {
  __shared__ __align__(16) char h1s[32 * 128];
  __shared__ float wls[32];
  int tid = threadIdx.x;
  int wave = tid >> 6, lane = tid & 63;
  int lr = lane & 31, hi = lane >> 5;
  bool ori = (int)blockIdx.x < 384;
  int row0 = (ori ? blockIdx.x : blockIdx.x - 384) * 32;
  const __bf16* xrow = xb + (ori ? (size_t)0 : (size_t)N_ * IND) + (size_t)row0 * IND;
  if (tid < 32) wls[tid] = ori ? (mask[row0 + tid] ? 0.f : 1.f) : dinv[row0 + tid];

  int col = wave * 32 + lr;
  // stage 1: h1 = relu(X@W1 + b1), out 32x64, this wave's 32 cols
  f32x16 acc = (f32x16)(0.f);
  const __bf16* wcol = W1T + (size_t)col * IND + hi * 8;
  const __bf16* arow = xrow + (size_t)lr * IND + hi * 8;
#pragma unroll
  for (int kk = 0; kk < 8; ++kk) {
    bf16x8 a = *(const bf16x8*)(arow + kk * 16);
    bf16x8 b = *(const bf16x8*)(wcol + kk * 16);
    acc = __builtin_amdgcn_mfma_f32_32x32x16_bf16(a, b, acc, 0, 0, 0);
  }
  float b1l = b1[col];
#pragma unroll
  for (int reg = 0; reg < 16; ++reg) {
    int rr = (reg & 3) + 8 * (reg >> 2) + 4 * hi;
    float v = fmaxf(acc[reg] + b1l, 0.f);
    lds_write_bf(h1s, rr, col, (__bf16)v);
  }
  __syncthreads();
  // stage 2: h = relu(h1@W2 + b2)
  f32x16 acc2 = (f32x16)(0.f);
  const __bf16* wcol2 = W2T + (size_t)col * HID + hi * 8;
#pragma unroll
  for (int kk = 0; kk < 4; ++kk) {
    bf16x8 a = lds_read_bf8(h1s, lr, kk * 16 + hi * 8);
    bf16x8 b = *(const bf16x8*)(wcol2 + kk * 16);
    acc2 = __builtin_amdgcn_mfma_f32_32x32x16_bf16(a, b, acc2, 0, 0, 0);
  }
  float b2l = b2[col];
  if (ori) {
    float part = 0.f;
#pragma unroll
    for (int reg = 0; reg < 16; ++reg) {
      int rr = (reg & 3) + 8 * (reg >> 2) + 4 * hi;
      float v = fmaxf(acc2[reg] + b2l, 0.f);
      part = fmaf(wls[rr], v, part);
    }
    atomicAdd(&gsum[col], part);
    if (tid == 0) {
      float wl = 0.f;
      for (int r = 0; r < 32; ++r) wl += wls[r];
      atomicAdd(&gsum[64], wl);
    }
  } else {
#pragma unroll
    for (int reg = 0; reg < 16; ++reg) {
      int rr = (reg & 3) + 8 * (reg >> 2) + 4 * hi;
      float v = fmaxf(acc2[reg] + b2l, 0.f);
      h_tr[(size_t)(row0 + rr) * HID + col] = v;
      xd[(size_t)(row0 + rr) * HID + col] = v * wls[rr];
    }
  }
}

// ---------------- y = x - segsum(xd[row], col)*dinv ; optionally yd = y*dinv ----------------
// 16 lanes per node, 4 nodes per wave, 16 nodes per block.
template <bool EMIT_D>
__global__ __launch_bounds__(256) void lap_kernel(
    const float* __restrict__ x, const float* __restrict__ xd,
    const float* __restrict__ d, const int* __restrict__ off,
    const int* __restrict__ csrRow, float* __restrict__ y, float* __restrict__ yd) {
  int lane = threadIdx.x & 63, wv = threadIdx.x >> 6;
  int g = lane >> 4, t = lane & 15;
  int c = blockIdx.x * 16 + wv * 4 + g;
  int s0 = off[c], s1 = off[c + 1];
  f4raw acc = (f4raw)(0.f);
  for (int i = s0; i < s1; ++i) {
    int r = csrRow[i];
    acc += *(const f4raw*)(xd + (size_t)r * HID + t * 4);
  }
  float dc = d[c];
  size_t idx = (size_t)c * HID + t * 4;
  f4raw v = *(const f4raw*)(x + idx) - acc * dc;
  *(f4raw*)(y + idx) = v;
  if (EMIT_D) *(f4raw*)(yd + idx) = v * dc;
}

// ---------------- q_global -> kq = scale*(Wk@qg), sb = scale*(bk.qg) ----------------
__global__ void qfinal_kernel(const float* __restrict__ gsum,
                              const float* __restrict__ Wq, const float* __restrict__ bq,
                              const float* __restrict__ Wk, const float* __restrict__ bk,
                              float* __restrict__ kq) {
  __shared__ float qg[QKD];
  int tid = threadIdx.x;  // 64 threads
  float wsum = gsum[64];
  float inv = 1.0f / fmaxf(wsum, 1.0f);
  if (tid < QKD) {
    float a = bq[tid] * wsum;
    for (int d0 = 0; d0 < HID; ++d0) a = fmaf(gsum[d0], Wq[d0 * QKD + tid], a);
    qg[tid] = a * inv;
  }
  __syncthreads();
  const float scale = 0.125f;  // 1/sqrt(HID)
  float a = 0.f;
  for (int q = 0; q < QKD; ++q) a = fmaf(Wk[tid * QKD + q], qg[q], a);
  kq[tid] = a * scale;
  if (tid == 0) {
    float sb = 0.f;
    for (int q = 0; q < QKD; ++q) sb = fmaf(bk[q], qg[q], sb);
    kq[64] = sb * scale;
  }
}

// ---------------- attention + z = zp@Wv+bv (MFMA) + x_hat = z@Wdx+bdx (MFMA) ----------------
// 32 rows/block, 128 threads (2 waves).
__global__ __launch_bounds__(128) void attnz_xhat_kernel(
    const float* __restrict__ h, const float* __restrict__ l1,
    const float* __restrict__ l2, const float* __restrict__ kqv,
    const __bf16* __restrict__ WvT, const float* __restrict__ bv,
    const __bf16* __restrict__ WdxT, const float* __restrict__ bdx,
    float* __restrict__ xhat, __bf16* __restrict__ zb) {
  __shared__ __align__(16) char zps[32 * 128];
  __shared__ __align__(16) char zsl[32 * 128];
  int tid = threadIdx.x;
  int wave = tid >> 6, lane = tid & 63;
  int g = lane >> 4, t = lane & 15;
  int row0 = blockIdx.x * 32;
  f4raw kq4 = *(const f4raw*)(kqv + t * 4);
  float sbias = kqv[64];
  // phase A: attention weights + zp (bf16, to swizzled LDS). 4 rows at a time.
#pragma unroll
  for (int it = 0; it < 4; ++it) {
    int r = wave * 16 + it * 4 + g;
    size_t idx = (size_t)(row0 + r) * HID + t * 4;
    f4raw hv = *(const f4raw*)(h + idx);
    f4raw v1 = *(const f4raw*)(l1 + idx);
    f4raw v2 = *(const f4raw*)(l2 + idx);
    f4raw av = 2.f * hv - v1;
    float s0 = av.x * kq4.x + av.y * kq4.y + av.z * kq4.z + av.w * kq4.w;
    float s1 = v1.x * kq4.x + v1.y * kq4.y + v1.z * kq4.z + v1.w * kq4.w;
    float s2 = v2.x * kq4.x + v2.y * kq4.y + v2.z * kq4.z + v2.w * kq4.w;
#pragma unroll
    for (int o = 1; o < 16; o <<= 1) {
      s0 += __shfl_xor(s0, o);
      s1 += __shfl_xor(s1, o);
      s2 += __shfl_xor(s2, o);
    }
    s0 += sbias; s1 += sbias; s2 += sbias;
    float m = fmaxf(s0, fmaxf(s1, s2));
    float e0 = __expf(s0 - m), e1 = __expf(s1 - m), e2 = __expf(s2 - m);
    float is = 1.f / (e0 + e1 + e2);
    f4raw zp = (e0 * av + e1 * v1 + e2 * v2) * is;
    bf16x4 z4;
    z4[0] = (__bf16)zp.x; z4[1] = (__bf16)zp.y; z4[2] = (__bf16)zp.z; z4[3] = (__bf16)zp.w;
    int off = (r * 128 + t * 8) ^ ((r & 7) << 4);
    *(bf16x4*)(zps + off) = z4;
  }
  __syncthreads();
  int lr = lane & 31, hi = lane >> 5;
  int col = wave * 32 + lr;
  // phase B: z = zp@Wv + bv  -> zb (global) + zsl (LDS, swizzled)
  f32x16 accz = (f32x16)(0.f);
  const __bf16* wv = WvT + (size_t)col * HID + hi * 8;
#pragma unroll
  for (int kk = 0; kk < 4; ++kk) {
    bf16x8 a = lds_read_bf8(zps, lr, kk * 16 + hi * 8);
    bf16x8 b = *(const bf16x8*)(wv + kk * 16);
    accz = __builtin_amdgcn_mfma_f32_32x32x16_bf16(a, b, accz, 0, 0, 0);
  }
  float bvl = bv[col];
#pragma unroll
  for (int reg = 0; reg < 16; ++reg) {
    int rr = (reg & 3) + 8 * (reg >> 2) + 4 * hi;
    __bf16 vb = (__bf16)(accz[reg] + bvl);
    zb[(size_t)(row0 + rr) * HID + col] = vb;
    lds_write_bf(zsl, rr, col, vb);
  }
  __syncthreads();
  // phase C: x_hat = z@Wdx + bdx; wave covers col tiles wave*32 and wave*32+64
#pragma unroll
  for (int tt = 0; tt < 2; ++tt) {
    int c0 = wave * 32 + tt * 64 + lr;
    f32x16 acx = (f32x16)(0.f);
    const __bf16* wd = WdxT + (size_t)c0 * HID + hi * 8;
#pragma unroll
    for (int kk = 0; kk < 4; ++kk) {
      bf16x8 a = lds_read_bf8(zsl, lr, kk * 16 + hi * 8);
      bf16x8 b = *(const bf16x8*)(wd + kk * 16);
      acx = __builtin_amdgcn_mfma_f32_32x32x16_bf16(a, b, acx, 0, 0, 0);
    }
    float bdl = bdx[c0];
#pragma unroll
    for (int reg = 0; reg < 16; ++reg) {
      int rr = (reg & 3) + 8 * (reg >> 2) + 4 * hi;
      xhat[(size_t)(row0 + rr) * IND + c0] = acx[reg] + bdl;
    }
  }
}

// ---------------- adj_hat = z @ z^T via bf16 MFMA ----------------
__global__ __launch_bounds__(256) void adj_mfma_kernel(
    const __bf16* __restrict__ z, float* __restrict__ out) {
  int tid = threadIdx.x;
  int wave = tid >> 6, lane = tid & 63;
  int wr = wave >> 1, wc = wave & 1;
  int rb = blockIdx.y, cb = blockIdx.x;
  int lr = lane & 31, hi = lane >> 5;

  size_t arow0 = (size_t)(rb * 128 + wr * 64 + lr) * HID;
  size_t arow1 = arow0 + (size_t)32 * HID;
  size_t brow0 = (size_t)(cb * 128 + wc * 64 + lr) * HID;
  size_t brow1 = brow0 + (size_t)32 * HID;
  int kbase = hi * 8;

  f32x16 acc00 = (f32x16)(0.f), acc01 = (f32x16)(0.f);
  f32x16 acc10 = (f32x16)(0.f), acc11 = (f32x16)(0.f);

#pragma unroll
  for (int kk = 0; kk < 4; ++kk) {
    int k0 = kk * 16 + kbase;
    bf16x8 a0 = *(const bf16x8*)(z + arow0 + k0);
    bf16x8 a1 = *(const bf16x8*)(z + arow1 + k0);
    bf16x8 b0 = *(const bf16x8*)(z + brow0 + k0);
    bf16x8 b1 = *(const bf16x8*)(z + brow1 + k0);
    acc00 = __builtin_amdgcn_mfma_f32_32x32x16_bf16(a0, b0, acc00, 0, 0, 0);
    acc01 = __builtin_amdgcn_mfma_f32_32x32x16_bf16(a0, b1, acc01, 0, 0, 0);
    acc10 = __builtin_amdgcn_mfma_f32_32x32x16_bf16(a1, b0, acc10, 0, 0, 0);
    acc11 = __builtin_amdgcn_mfma_f32_32x32x16_bf16(a1, b1, acc11, 0, 0, 0);
  }

  int colb = cb * 128 + wc * 64 + lr;
  int rowb = rb * 128 + wr * 64 + 4 * hi;
#pragma unroll
  for (int reg = 0; reg < 16; ++reg) {
    int rr = (reg & 3) + 8 * (reg >> 2);
    size_t r0 = (size_t)(rowb + rr);
    __builtin_nontemporal_store(acc00[reg], out + r0 * N_ + colb);
    __builtin_nontemporal_store(acc01[reg], out + r0 * N_ + colb + 32);
    __builtin_nontemporal_store(acc10[reg], out + (r0 + 32) * N_ + colb);
    __builtin_nontemporal_store(acc11[reg], out + (r0 + 32) * N_ + colb + 32);
  }
}

extern "C" void kernel_launch(void* const* d_in, const int* in_sizes, int n_in,
                              void* d_out, int out_size, void* d_ws, size_t ws_size,
                              hipStream_t stream) {
  const float* x_train = (const float*)d_in[0];
  const float* x_ori   = (const float*)d_in[1];
  const int*   ei      = (const int*)d_in[2];
  const unsigned char* mask = (const unsigned char*)d_in[3];
  const float* W1  = (const float*)d_in[4];
  const float* b1  = (const float*)d_in[5];
  const float* W2  = (const float*)d_in[6];
  const float* b2  = (const float*)d_in[7];
  const float* Wq  = (const float*)d_in[8];
  const float* bq  = (const float*)d_in[9];
  const float* Wk  = (const float*)d_in[10];
  const float* bk  = (const float*)d_in[11];
  const float* Wv  = (const float*)d_in[12];
  const float* bv  = (const float*)d_in[13];
  const float* Wdx = (const float*)d_in[14];
  const float* bdx = (const float*)d_in[15];

  char* ws = (char*)d_ws;
  size_t o = 0;
  auto alloc = [&](size_t bytes) -> void* {
    void* p = ws + o;
    o += (bytes + 255) & ~(size_t)255;
    return p;
  };
  __bf16* xb    = (__bf16*)alloc((size_t)2 * N_ * IND * 2);
  __bf16* W1T   = (__bf16*)alloc((size_t)IND * HID * 2);
  __bf16* W2T   = (__bf16*)alloc((size_t)HID * HID * 2);
  __bf16* WvT   = (__bf16*)alloc((size_t)HID * HID * 2);
  __bf16* WdxT  = (__bf16*)alloc((size_t)HID * IND * 2);
  float* h_tr   = (float*)alloc((size_t)N_ * HID * 4);
  float* lap1   = (float*)alloc((size_t)N_ * HID * 4);
  float* lap1d  = (float*)alloc((size_t)N_ * HID * 4);
  float* lap2   = (float*)alloc((size_t)N_ * HID * 4);
  float* xd     = (float*)alloc((size_t)N_ * HID * 4);
  __bf16* zb    = (__bf16*)alloc((size_t)N_ * HID * 2);
  float* dinv   = (float*)alloc((size_t)N_ * 4);
  int*   zero0  = (int*)alloc((size_t)(2 * N_ + 65) * 4);
  int*   degRow = zero0;
  int*   cntCol = zero0 + N_;
  float* gsum   = (float*)(zero0 + 2 * N_);
  int*   off    = (int*)alloc((size_t)(N_ + 1) * 4);
  int*   cursor = (int*)alloc((size_t)N_ * 4);
  int*   csrRow = (int*)alloc((size_t)E_ * 4);
  float* kq     = (float*)alloc(65 * 4);

  const int* row = ei;
  const int* col = ei + E_;

  (void)hipMemsetAsync(zero0, 0, (size_t)(2 * N_ + 65) * 4, stream);

  prep_kernel<<<1540, 256, 0, stream>>>(x_ori, x_train, W1, W2, Wv, Wdx,
                                        xb, W1T, W2T, WvT, WdxT);
  hist_kernel<<<E_ / 256, 256, 0, stream>>>(row, col, degRow, cntCol);
  scan_kernel<<<1, 1024, 0, stream>>>(cntCol, degRow, off, cursor, dinv);
  scatter_kernel<<<E_ / 256, 256, 0, stream>>>(row, col, cursor, csrRow);

  enc_mfma_kernel<<<768, 128, 0, stream>>>(xb, W1T, b1, W2T, b2, dinv, mask,
                                           h_tr, xd, gsum);

  lap_kernel<true><<<N_ / 16, 256, 0, stream>>>(h_tr, xd, dinv, off, csrRow, lap1, lap1d);
  lap_kernel<false><<<N_ / 16, 256, 0, stream>>>(lap1, lap1d, dinv, off, csrRow, lap2, nullptr);

  qfinal_kernel<<<1, 64, 0, stream>>>(gsum, Wq, bq, Wk, bk, kq);

  float* outp = (float*)d_out;
  attnz_xhat_kernel<<<N_ / 32, 128, 0, stream>>>(h_tr, lap1, lap2, kq, WvT, bv,
                                                 WdxT, bdx, outp, zb);
  adj_mfma_kernel<<<dim3(96, 96), 256, 0, stream>>>(zb, outp + (size_t)N_ * IND);
}

// Round 6
// 269.990 us; speedup vs baseline: 1.9746x; 1.1077x over previous
//
#include <hip/hip_runtime.h>
#include <hip/hip_bf16.h>

constexpr int N_  = 12288;
constexpr int E_  = 393216;
constexpr int IND = 128;
constexpr int HID = 64;
constexpr int QKD = 32;

typedef __attribute__((ext_vector_type(4))) float f4raw;
typedef __attribute__((ext_vector_type(8))) __bf16 bf16x8;
typedef __attribute__((ext_vector_type(4))) __bf16 bf16x4;
typedef __attribute__((ext_vector_type(16))) float f32x16;

// LDS bf16 tile helpers: [32 rows][64 cols] = 128 B/row, XOR-swizzled
// (byte ^= (row&7)<<4) so stride-128B column reads spread across banks.
__device__ inline bf16x8 lds_read_bf8(const char* base, int row, int k) {
  int off = (row * 128 + k * 2) ^ ((row & 7) << 4);
  uint4 u = *(const uint4*)(base + off);
  union { uint4 u; bf16x8 v; } c; c.u = u; return c.v;
}
__device__ inline void lds_write_bf(char* base, int row, int col, __bf16 v) {
  int off = (row * 128 + col * 2) ^ ((row & 7) << 4);
  *(__bf16*)(base + off) = v;
}

// ---------------- K1: hist (edges) + bf16 prep (x, weights), fused ----------------
__global__ __launch_bounds__(256) void prep_hist_kernel(
    const float* __restrict__ xo, const float* __restrict__ xt,
    const int* __restrict__ row, const int* __restrict__ col,
    const float* __restrict__ W1, const float* __restrict__ W2,
    const float* __restrict__ Wv, const float* __restrict__ Wdx,
    __bf16* __restrict__ xb, __bf16* __restrict__ W1T, __bf16* __restrict__ W2T,
    __bf16* __restrict__ WvT, __bf16* __restrict__ WdxT,
    int* degRow, int* cntCol) {
  int b = blockIdx.x, tid = threadIdx.x;
  if (b < 1536) {
    int e = b * 256 + tid;
    atomicAdd(&degRow[row[e]], 1);
    atomicAdd(&cntCol[col[e]], 1);
  } else if (b < 3072) {
    size_t base = (size_t)(b - 1536) * 2048 + (size_t)tid * 8;
    const size_t half = (size_t)N_ * IND;
    const float* src = (base < half) ? (xo + base) : (xt + (base - half));
    f4raw v0 = *(const f4raw*)(src);
    f4raw v1 = *(const f4raw*)(src + 4);
    bf16x8 o;
    o[0] = (__bf16)v0.x; o[1] = (__bf16)v0.y; o[2] = (__bf16)v0.z; o[3] = (__bf16)v0.w;
    o[4] = (__bf16)v1.x; o[5] = (__bf16)v1.y; o[6] = (__bf16)v1.z; o[7] = (__bf16)v1.w;
    *(bf16x8*)(xb + base) = o;
  } else if (b == 3072) {
    for (int e = tid; e < IND * HID; e += 256) {
      int c = e >> 7, k = e & 127;           // W1T[c][k]
      W1T[e] = (__bf16)W1[k * HID + c];
    }
  } else if (b == 3073) {
    for (int e = tid; e < HID * HID; e += 256) {
      int c = e >> 6, k = e & 63;
      W2T[e] = (__bf16)W2[k * HID + c];
    }
  } else if (b == 3074) {
    for (int e = tid; e < HID * HID; e += 256) {
      int c = e >> 6, k = e & 63;
      WvT[e] = (__bf16)Wv[k * HID + c];
    }
  } else {
    for (int e = tid; e < HID * IND; e += 256) {
      int c = e >> 6, k = e & 63;            // WdxT[c][k]
      WdxT[e] = (__bf16)Wdx[k * IND + c];
    }
  }
}

// ---------------- K2: exclusive scan over cntCol + dinv (single block) ----------------
__global__ __launch_bounds__(1024) void scan_kernel(const int* __restrict__ cnt,
                                                    const int* __restrict__ deg,
                                                    int* __restrict__ off,
                                                    int* __restrict__ cursor,
                                                    float* __restrict__ dinv) {
  __shared__ int sd[1024];
  int tid = threadIdx.x;
  int base = tid * 12;
  int local[12];
  int s = 0;
#pragma unroll
  for (int i = 0; i < 12; ++i) { local[i] = cnt[base + i]; s += local[i]; }
  sd[tid] = s;
  __syncthreads();
  for (int o = 1; o < 1024; o <<= 1) {
    int v = (tid >= o) ? sd[tid - o] : 0;
    __syncthreads();
    sd[tid] += v;
    __syncthreads();
  }
  int run = sd[tid] - s;
#pragma unroll
  for (int i = 0; i < 12; ++i) {
    off[base + i] = run;
    cursor[base + i] = run;
    run += local[i];
  }
  if (tid == 1023) off[N_] = run;
#pragma unroll
  for (int i = 0; i < 12; ++i) {
    int ii = base + i;
    dinv[ii] = rsqrtf((float)max(deg[ii], 1));
  }
}

// ---------------- K3: CSR scatter + MFMA encoder (+gsum, xd), fused ----------------
// blocks [0,1536): scatter. blocks [1536,1920): encoder, 64 rows each
// (4 waves: wave pair p covers rows p*32..p*32+31, w2 = col half).
__global__ __launch_bounds__(256) void scatter_enc_kernel(
    const int* __restrict__ row, const int* __restrict__ col,
    int* cursor, int* __restrict__ csrRow,
    const __bf16* __restrict__ xb,
    const __bf16* __restrict__ W1T, const float* __restrict__ b1,
    const __bf16* __restrict__ W2T, const float* __restrict__ b2,
    const float* __restrict__ dinv, const unsigned char* __restrict__ mask,
    float* __restrict__ h_tr, float* __restrict__ xd, float* __restrict__ gsum) {
  __shared__ __align__(16) char h1s[2][32 * 128];
  __shared__ float wls[64];
  int b = blockIdx.x, tid = threadIdx.x;
  if (b < 1536) {
    int e = b * 256 + tid;
    int c = col[e];
    int p = atomicAdd(&cursor[c], 1);
    csrRow[p] = row[e];
    return;
  }
  int bb = b - 1536;             // 0..383
  bool ori = bb < 192;
  int row0 = (ori ? bb : bb - 192) * 64;
  const __bf16* xrow = xb + (ori ? (size_t)0 : (size_t)N_ * IND) + (size_t)row0 * IND;
  if (tid < 64) wls[tid] = ori ? (mask[row0 + tid] ? 0.f : 1.f) : dinv[row0 + tid];
  int wave = tid >> 6, lane = tid & 63;
  int p = wave >> 1, w2 = wave & 1;
  int lr = lane & 31, hi = lane >> 5;
  int colc = w2 * 32 + lr;
  // stage 1: h1 = relu(X@W1 + b1) for this wave's 32 rows x 32 cols
  f32x16 acc = (f32x16)(0.f);
  const __bf16* wcol = W1T + (size_t)colc * IND + hi * 8;
  const __bf16* arow = xrow + (size_t)(p * 32 + lr) * IND + hi * 8;
#pragma unroll
  for (int kk = 0; kk < 8; ++kk) {
    bf16x8 a = *(const bf16x8*)(arow + kk * 16);
    bf16x8 bq = *(const bf16x8*)(wcol + kk * 16);
    acc = __builtin_amdgcn_mfma_f32_32x32x16_bf16(a, bq, acc, 0, 0, 0);
  }
  float b1l = b1[colc];
#pragma unroll
  for (int reg = 0; reg < 16; ++reg) {
    int rr = (reg & 3) + 8 * (reg >> 2) + 4 * hi;
    float v = fmaxf(acc[reg] + b1l, 0.f);
    lds_write_bf(h1s[p], rr, colc, (__bf16)v);
  }
  __syncthreads();
  // stage 2: h = relu(h1@W2 + b2)
  f32x16 acc2 = (f32x16)(0.f);
  const __bf16* wcol2 = W2T + (size_t)colc * HID + hi * 8;
#pragma unroll
  for (int kk = 0; kk < 4; ++kk) {
    bf16x8 a = lds_read_bf8(h1s[p], lr, kk * 16 + hi * 8);
    bf16x8 bq = *(const bf16x8*)(wcol2 + kk * 16);
    acc2 = __builtin_amdgcn_mfma_f32_32x32x16_bf16(a, bq, acc2, 0, 0, 0);
  }
  float b2l = b2[colc];
  if (ori) {
    float part = 0.f;
#pragma unroll
    for (int reg = 0; reg < 16; ++reg) {
      int rr = (reg & 3) + 8 * (reg >> 2) + 4 * hi;
      float v = fmaxf(acc2[reg] + b2l, 0.f);
      part = fmaf(wls[p * 32 + rr], v, part);
    }
    atomicAdd(&gsum[colc], part);
    if (tid == 0) {
      float wl = 0.f;
      for (int r = 0; r < 64; ++r) wl += wls[r];
      atomicAdd(&gsum[64], wl);
    }
  } else {
#pragma unroll
    for (int reg = 0; reg < 16; ++reg) {
      int rr = (reg & 3) + 8 * (reg >> 2) + 4 * hi;
      float v = fmaxf(acc2[reg] + b2l, 0.f);
      int gr = row0 + p * 32 + rr;
      h_tr[(size_t)gr * HID + colc] = v;
      xd[(size_t)gr * HID + colc] = v * wls[p * 32 + rr];
    }
  }
}

// ---------------- K4: lap1d = xd - segsum(xd[row],col)*d^2 ----------------
// 16 lanes per node, 4 nodes/wave, 16 nodes/block; 2-edge unrolled gather.
__global__ __launch_bounds__(256) void lap1_kernel(
    const float* __restrict__ xd, const float* __restrict__ dinv,
    const int* __restrict__ off, const int* __restrict__ csrRow,
    float* __restrict__ lap1d) {
  int lane = threadIdx.x & 63, wv = threadIdx.x >> 6;
  int g = lane >> 4, t = lane & 15;
  int c = blockIdx.x * 16 + wv * 4 + g;
  int s0 = off[c], s1 = off[c + 1];
  f4raw a0 = (f4raw)(0.f), a1 = (f4raw)(0.f);
  int i = s0;
  for (; i + 1 < s1; i += 2) {
    int r0 = csrRow[i], r1 = csrRow[i + 1];
    a0 += *(const f4raw*)(xd + (size_t)r0 * HID + t * 4);
    a1 += *(const f4raw*)(xd + (size_t)r1 * HID + t * 4);
  }
  if (i < s1) {
    int r0 = csrRow[i];
    a0 += *(const f4raw*)(xd + (size_t)r0 * HID + t * 4);
  }
  float d = dinv[c];
  size_t idx = (size_t)c * HID + t * 4;
  *(f4raw*)(lap1d + idx) = *(const f4raw*)(xd + idx) - (a0 + a1) * (d * d);
}

// ---------------- K5: lap2 = lap1d/d - segsum(lap1d[row],col)*d ----------------
__global__ __launch_bounds__(256) void lap2_kernel(
    const float* __restrict__ lap1d, const float* __restrict__ dinv,
    const int* __restrict__ off, const int* __restrict__ csrRow,
    float* __restrict__ lap2) {
  int lane = threadIdx.x & 63, wv = threadIdx.x >> 6;
  int g = lane >> 4, t = lane & 15;
  int c = blockIdx.x * 16 + wv * 4 + g;
  int s0 = off[c], s1 = off[c + 1];
  f4raw a0 = (f4raw)(0.f), a1 = (f4raw)(0.f);
  int i = s0;
  for (; i + 1 < s1; i += 2) {
    int r0 = csrRow[i], r1 = csrRow[i + 1];
    a0 += *(const f4raw*)(lap1d + (size_t)r0 * HID + t * 4);
    a1 += *(const f4raw*)(lap1d + (size_t)r1 * HID + t * 4);
  }
  if (i < s1) {
    int r0 = csrRow[i];
    a0 += *(const f4raw*)(lap1d + (size_t)r0 * HID + t * 4);
  }
  float d = dinv[c];
  float rd = 1.0f / d;
  size_t idx = (size_t)c * HID + t * 4;
  *(f4raw*)(lap2 + idx) = *(const f4raw*)(lap1d + idx) * rd - (a0 + a1) * d;
}

// ---------------- K6: inline-qfinal + attention + z=zp@Wv+bv + x_hat=z@Wdx+bdx ----------------
// 32 rows/block, 128 threads (2 waves).
__global__ __launch_bounds__(128) void attnz_xhat_kernel(
    const float* __restrict__ h, const float* __restrict__ lap1d,
    const float* __restrict__ lap2, const float* __restrict__ dinv,
    const float* __restrict__ gsum,
    const float* __restrict__ Wq, const float* __restrict__ bq,
    const float* __restrict__ Wk, const float* __restrict__ bk,
    const __bf16* __restrict__ WvT, const float* __restrict__ bv,
    const __bf16* __restrict__ WdxT, const float* __restrict__ bdx,
    float* __restrict__ xhat, __bf16* __restrict__ zb) {
  __shared__ __align__(16) char zps[32 * 128];
  __shared__ __align__(16) char zsl[32 * 128];
  __shared__ float qg[QKD];
  __shared__ float kqs[72];
  int tid = threadIdx.x;
  // inline qfinal (every block recomputes; gsum is final and identical)
  float wsum = gsum[64];
  if (tid < QKD) {
    float inv = 1.0f / fmaxf(wsum, 1.0f);
    float a = bq[tid] * wsum;
    for (int d0 = 0; d0 < HID; ++d0) a = fmaf(gsum[d0], Wq[d0 * QKD + tid], a);
    qg[tid] = a * inv;
  }
  __syncthreads();
  if (tid < 64) {
    float a = 0.f;
    for (int q = 0; q < QKD; ++q) a = fmaf(Wk[tid * QKD + q], qg[q], a);
    kqs[tid] = a * 0.125f;
  } else if (tid == 64) {
    float sb = 0.f;
    for (int q = 0; q < QKD; ++q) sb = fmaf(bk[q], qg[q], sb);
    kqs[64] = sb * 0.125f;
  }
  __syncthreads();
  int wave = tid >> 6, lane = tid & 63;
  int g = lane >> 4, t = lane & 15;
  int row0 = blockIdx.x * 32;
  f4raw kq4 = *(const f4raw*)(&kqs[t * 4]);
  float sbias = kqs[64];
  // phase A: attention weights + zp (bf16, swizzled LDS). 4 rows/iter.
#pragma unroll
  for (int it = 0; it < 4; ++it) {
    int r = wave * 16 + it * 4 + g;
    int c = row0 + r;
    size_t idx = (size_t)c * HID + t * 4;
    float d = dinv[c];
    float rd = 1.0f / d;
    f4raw hv = *(const f4raw*)(h + idx);
    f4raw v1 = *(const f4raw*)(lap1d + idx) * rd;
    f4raw v2 = *(const f4raw*)(lap2 + idx);
    f4raw av = 2.f * hv - v1;
    float s0 = av.x * kq4.x + av.y * kq4.y + av.z * kq4.z + av.w * kq4.w;
    float s1 = v1.x * kq4.x + v1.y * kq4.y + v1.z * kq4.z + v1.w * kq4.w;
    float s2 = v2.x * kq4.x + v2.y * kq4.y + v2.z * kq4.z + v2.w * kq4.w;
#pragma unroll
    for (int o = 1; o < 16; o <<= 1) {
      s0 += __shfl_xor(s0, o);
      s1 += __shfl_xor(s1, o);
      s2 += __shfl_xor(s2, o);
    }
    s0 += sbias; s1 += sbias; s2 += sbias;
    float m = fmaxf(s0, fmaxf(s1, s2));
    float e0 = __expf(s0 - m), e1 = __expf(s1 - m), e2 = __expf(s2 - m);
    float is = 1.f / (e0 + e1 + e2);
    f4raw zp = (e0 * av + e1 * v1 + e2 * v2) * is;
    bf16x4 z4;
    z4[0] = (__bf16)zp.x; z4[1] = (__bf16)zp.y; z4[2] = (__bf16)zp.z; z4[3] = (__bf16)zp.w;
    int off = (r * 128 + t * 8) ^ ((r & 7) << 4);
    *(bf16x4*)(zps + off) = z4;
  }
  __syncthreads();
  int lr = lane & 31, hi = lane >> 5;
  int col = wave * 32 + lr;
  // phase B: z = zp@Wv + bv -> zb + zsl
  f32x16 accz = (f32x16)(0.f);
  const __bf16* wv = WvT + (size_t)col * HID + hi * 8;
#pragma unroll
  for (int kk = 0; kk < 4; ++kk) {
    bf16x8 a = lds_read_bf8(zps, lr, kk * 16 + hi * 8);
    bf16x8 bq = *(const bf16x8*)(wv + kk * 16);
    accz = __builtin_amdgcn_mfma_f32_32x32x16_bf16(a, bq, accz, 0, 0, 0);
  }
  float bvl = bv[col];
#pragma unroll
  for (int reg = 0; reg < 16; ++reg) {
    int rr = (reg & 3) + 8 * (reg >> 2) + 4 * hi;
    __bf16 vb = (__bf16)(accz[reg] + bvl);
    zb[(size_t)(row0 + rr) * HID + col] = vb;
    lds_write_bf(zsl, rr, col, vb);
  }
  __syncthreads();
  // phase C: x_hat = z@Wdx + bdx
#pragma unroll
  for (int tt = 0; tt < 2; ++tt) {
    int c0 = wave * 32 + tt * 64 + lr;
    f32x16 acx = (f32x16)(0.f);
    const __bf16* wd = WdxT + (size_t)c0 * HID + hi * 8;
#pragma unroll
    for (int kk = 0; kk < 4; ++kk) {
      bf16x8 a = lds_read_bf8(zsl, lr, kk * 16 + hi * 8);
      bf16x8 bq = *(const bf16x8*)(wd + kk * 16);
      acx = __builtin_amdgcn_mfma_f32_32x32x16_bf16(a, bq, acx, 0, 0, 0);
    }
    float bdl = bdx[c0];
#pragma unroll
    for (int reg = 0; reg < 16; ++reg) {
      int rr = (reg & 3) + 8 * (reg >> 2) + 4 * hi;
      xhat[(size_t)(row0 + rr) * IND + c0] = acx[reg] + bdl;
    }
  }
}

// ---------------- K7: adj_hat = z @ z^T via bf16 MFMA ----------------
__global__ __launch_bounds__(256) void adj_mfma_kernel(
    const __bf16* __restrict__ z, float* __restrict__ out) {
  int tid = threadIdx.x;
  int wave = tid >> 6, lane = tid & 63;
  int wr = wave >> 1, wc = wave & 1;
  int rb = blockIdx.y, cb = blockIdx.x;
  int lr = lane & 31, hi = lane >> 5;

  size_t arow0 = (size_t)(rb * 128 + wr * 64 + lr) * HID;
  size_t arow1 = arow0 + (size_t)32 * HID;
  size_t brow0 = (size_t)(cb * 128 + wc * 64 + lr) * HID;
  size_t brow1 = brow0 + (size_t)32 * HID;
  int kbase = hi * 8;

  f32x16 acc00 = (f32x16)(0.f), acc01 = (f32x16)(0.f);
  f32x16 acc10 = (f32x16)(0.f), acc11 = (f32x16)(0.f);

#pragma unroll
  for (int kk = 0; kk < 4; ++kk) {
    int k0 = kk * 16 + kbase;
    bf16x8 a0 = *(const bf16x8*)(z + arow0 + k0);
    bf16x8 a1 = *(const bf16x8*)(z + arow1 + k0);
    bf16x8 b0 = *(const bf16x8*)(z + brow0 + k0);
    bf16x8 b1 = *(const bf16x8*)(z + brow1 + k0);
    acc00 = __builtin_amdgcn_mfma_f32_32x32x16_bf16(a0, b0, acc00, 0, 0, 0);
    acc01 = __builtin_amdgcn_mfma_f32_32x32x16_bf16(a0, b1, acc01, 0, 0, 0);
    acc10 = __builtin_amdgcn_mfma_f32_32x32x16_bf16(a1, b0, acc10, 0, 0, 0);
    acc11 = __builtin_amdgcn_mfma_f32_32x32x16_bf16(a1, b1, acc11, 0, 0, 0);
  }

  int colb = cb * 128 + wc * 64 + lr;
  int rowb = rb * 128 + wr * 64 + 4 * hi;
#pragma unroll
  for (int reg = 0; reg < 16; ++reg) {
    int rr = (reg & 3) + 8 * (reg >> 2);
    size_t r0 = (size_t)(rowb + rr);
    __builtin_nontemporal_store(acc00[reg], out + r0 * N_ + colb);
    __builtin_nontemporal_store(acc01[reg], out + r0 * N_ + colb + 32);
    __builtin_nontemporal_store(acc10[reg], out + (r0 + 32) * N_ + colb);
    __builtin_nontemporal_store(acc11[reg], out + (r0 + 32) * N_ + colb + 32);
  }
}

extern "C" void kernel_launch(void* const* d_in, const int* in_sizes, int n_in,
                              void* d_out, int out_size, void* d_ws, size_t ws_size,
                              hipStream_t stream) {
  const float* x_train = (const float*)d_in[0];
  const float* x_ori   = (const float*)d_in[1];
  const int*   ei      = (const int*)d_in[2];
  const unsigned char* mask = (const unsigned char*)d_in[3];
  const float* W1  = (const float*)d_in[4];
  const float* b1  = (const float*)d_in[5];
  const float* W2  = (const float*)d_in[6];
  const float* b2  = (const float*)d_in[7];
  const float* Wq  = (const float*)d_in[8];
  const float* bq  = (const float*)d_in[9];
  const float* Wk  = (const float*)d_in[10];
  const float* bk  = (const float*)d_in[11];
  const float* Wv  = (const float*)d_in[12];
  const float* bv  = (const float*)d_in[13];
  const float* Wdx = (const float*)d_in[14];
  const float* bdx = (const float*)d_in[15];

  char* ws = (char*)d_ws;
  size_t o = 0;
  auto alloc = [&](size_t bytes) -> void* {
    void* p = ws + o;
    o += (bytes + 255) & ~(size_t)255;
    return p;
  };
  __bf16* xb    = (__bf16*)alloc((size_t)2 * N_ * IND * 2);
  __bf16* W1T   = (__bf16*)alloc((size_t)IND * HID * 2);
  __bf16* W2T   = (__bf16*)alloc((size_t)HID * HID * 2);
  __bf16* WvT   = (__bf16*)alloc((size_t)HID * HID * 2);
  __bf16* WdxT  = (__bf16*)alloc((size_t)HID * IND * 2);
  float* h_tr   = (float*)alloc((size_t)N_ * HID * 4);
  float* lap1d  = (float*)alloc((size_t)N_ * HID * 4);
  float* lap2   = (float*)alloc((size_t)N_ * HID * 4);
  float* xd     = (float*)alloc((size_t)N_ * HID * 4);
  __bf16* zb    = (__bf16*)alloc((size_t)N_ * HID * 2);
  float* dinv   = (float*)alloc((size_t)N_ * 4);
  int*   zero0  = (int*)alloc((size_t)(2 * N_ + 65) * 4);
  int*   degRow = zero0;
  int*   cntCol = zero0 + N_;
  float* gsum   = (float*)(zero0 + 2 * N_);
  int*   off    = (int*)alloc((size_t)(N_ + 1) * 4);
  int*   cursor = (int*)alloc((size_t)N_ * 4);
  int*   csrRow = (int*)alloc((size_t)E_ * 4);

  const int* row = ei;
  const int* col = ei + E_;

  (void)hipMemsetAsync(zero0, 0, (size_t)(2 * N_ + 65) * 4, stream);

  prep_hist_kernel<<<3076, 256, 0, stream>>>(x_ori, x_train, row, col,
                                             W1, W2, Wv, Wdx,
                                             xb, W1T, W2T, WvT, WdxT,
                                             degRow, cntCol);
  scan_kernel<<<1, 1024, 0, stream>>>(cntCol, degRow, off, cursor, dinv);
  scatter_enc_kernel<<<1920, 256, 0, stream>>>(row, col, cursor, csrRow,
                                               xb, W1T, b1, W2T, b2,
                                               dinv, mask, h_tr, xd, gsum);
  lap1_kernel<<<N_ / 16, 256, 0, stream>>>(xd, dinv, off, csrRow, lap1d);
  lap2_kernel<<<N_ / 16, 256, 0, stream>>>(lap1d, dinv, off, csrRow, lap2);

  float* outp = (float*)d_out;
  attnz_xhat_kernel<<<N_ / 32, 128, 0, stream>>>(h_tr, lap1d, lap2, dinv, gsum,
                                                 Wq, bq, Wk, bk, WvT, bv,
                                                 WdxT, bdx, outp, zb);
  adj_mfma_kernel<<<dim3(96, 96), 256, 0, stream>>>(zb, outp + (size_t)N_ * IND);
}